// Round 9
// baseline (1602.164 us; speedup 1.0000x reference)
//
#include <hip/hip_runtime.h>
#include <hip/hip_bf16.h>

typedef __hip_bfloat16 bf16;
typedef __bf16 bf16x8 __attribute__((ext_vector_type(8)));
typedef float  f32x4  __attribute__((ext_vector_type(4)));

#define N_NODES 16384
#define HDIM    256
#define NE      131072
#define NE2     147456   // NE + N self loops

__device__ __forceinline__ float b2f(bf16 v){ return __bfloat162float(v); }
__device__ __forceinline__ bf16  f2b(float v){ return __float2bfloat16(v); }
__device__ __forceinline__ float us2f(unsigned short u){
  union { unsigned int i; float f; } c; c.i = ((unsigned int)u) << 16; return c.f;
}
__device__ __forceinline__ unsigned short f2us(float f){
  bf16 h = __float2bfloat16(f);
  unsigned short u; __builtin_memcpy(&u, &h, 2); return u;
}
__device__ __forceinline__ float gelu_f(float x){
  return 0.5f * x * (1.0f + erff(x * 0.7071067811865476f));
}
__device__ __forceinline__ float wave_sum(float v){
  #pragma unroll
  for (int o = 32; o > 0; o >>= 1) v += __shfl_xor(v, o);
  return v;
}
__device__ __forceinline__ float wave_max(float v){
  #pragma unroll
  for (int o = 32; o > 0; o >>= 1) v = fmaxf(v, __shfl_xor(v, o));
  return v;
}

__device__ __forceinline__ float4 load4(const float* p){ return *(const float4*)p; }
__device__ __forceinline__ float4 load4(const bf16* p){
  ushort4 u = *(const ushort4*)p;
  return make_float4(us2f(u.x), us2f(u.y), us2f(u.z), us2f(u.w));
}
__device__ __forceinline__ void store4(float* p, float4 v){ *(float4*)p = v; }
__device__ __forceinline__ void store4(bf16* p, float4 v){
  ushort4 u = make_ushort4(f2us(v.x), f2us(v.y), f2us(v.z), f2us(v.w));
  *(ushort4*)p = u;
}
__device__ __forceinline__ void storev(float* p, float4 v){ *(float4*)p = v; }
__device__ __forceinline__ void storev(bf16*  p, float4 v){ store4(p, v); }

// async 16B/lane global -> LDS (lds dest = wave-uniform base + lane*16)
__device__ __forceinline__ void async_ld16(const bf16* g, unsigned short* l){
  __builtin_amdgcn_global_load_lds(
      (const __attribute__((address_space(1))) void*)g,
      (__attribute__((address_space(3))) void*)l, 16, 0, 0);
}

// ---------------------------------------------------------------------------
// dtype detection + normalization.  flags[1] = input-is-f32
// ---------------------------------------------------------------------------
__global__ void detect_dtype(const unsigned short* __restrict__ x, int n, int* __restrict__ flags){
  int i = blockIdx.x * 256 + threadIdx.x;
  if (i < n) {
    unsigned short u = x[i];
    if ((u & 0x7F80) == 0x7F80) atomicOr(&flags[1], 1);
  }
}
struct ConvArgs {
  const void* src[35];
  unsigned short* dst[35];
  int cumg[36];
  int n[35];
};
__global__ void conv_all4(ConvArgs a, const int* __restrict__ flags){
  int gi = blockIdx.x * 256 + threadIdx.x;
  if (gi >= a.cumg[35]) return;
  int lo = 0, hi = 34;
  while (lo < hi) { int mid = (lo + hi + 1) >> 1; if (gi >= a.cumg[mid]) lo = mid; else hi = mid - 1; }
  int e0 = (gi - a.cumg[lo]) << 2;
  int n = a.n[lo];
  unsigned short* d = a.dst[lo];
  if (flags[1]) {
    const float* s = (const float*)a.src[lo];
    if (e0 + 4 <= n) {
      float4 v = *(const float4*)(s + e0);
      *(ushort4*)(d + e0) = make_ushort4(f2us(v.x), f2us(v.y), f2us(v.z), f2us(v.w));
    } else {
      for (int t = 0; t < n - e0; ++t) d[e0 + t] = f2us(s[e0 + t]);
    }
  } else {
    const unsigned short* s = (const unsigned short*)a.src[lo];
    if (e0 + 4 <= n) *(ushort4*)(d + e0) = *(const ushort4*)(s + e0);
    else for (int t = 0; t < n - e0; ++t) d[e0 + t] = s[e0 + t];
  }
}
__global__ void emit_out(const unsigned short* __restrict__ stage, void* __restrict__ out,
                         int n, const int* __restrict__ flags){
  int i = blockIdx.x * 256 + threadIdx.x;
  if (i >= n) return;
  if (flags[1]) ((float*)out)[i] = us2f(stage[i]);
  else          ((unsigned short*)out)[i] = stage[i];
}
__global__ void write_sentinel(bf16* out, float v){ out[threadIdx.x] = f2b(v); }

// ---------------------------------------------------------------------------
// gemm2: MFMA bf16 NT GEMM with async global->LDS staging (BK=64, XOR swizzle)
// and LDS-transposed vectorized epilogue. C = A[M,K] * W[Nn,K]^T (+bias)...
// FLAGS: 1 = gelu, 2 = residual add (res f32), 4 = also store bf16 mirror C2,
//        8 = GAT als/ald fused epilogue.
// M%128==0, Nn%128==0, K%64==0.
// NOTE: XCD blockIdx swizzle measured HARMFUL here (R7: +60% on gemm2 —
// operands are L2/L3-resident, no HBM win available). Natural order kept.
// ---------------------------------------------------------------------------
#define GF_GELU 1
#define GF_RES  2
#define GF_MIR  4
#define GF_ALS  8

template<typename TO, int FLAGS>
__global__ __launch_bounds__(256) void gemm2(
    const bf16* __restrict__ A, const bf16* __restrict__ W,
    const bf16* __restrict__ bias, const float* __restrict__ res,
    TO* __restrict__ C, bf16* __restrict__ C2, int M, int Nn, int K,
    const bf16* __restrict__ asp, const bf16* __restrict__ adp,
    float* __restrict__ alsp)
{
  __shared__ __align__(16) char ldsraw[36864];   // staging 32 KB | epilogue 36 KB
  unsigned short* sA = (unsigned short*)ldsraw;  // 128 rows x 64 shorts
  unsigned short* sB = sA + 128 * 64;
  const int tid = threadIdx.x;
  const int wave = tid >> 6, lane = tid & 63;
  const int quad = lane >> 4, l16 = lane & 15;
  const int wm = wave & 1, wn = wave >> 1;
  const int row0 = blockIdx.y << 7, col0 = blockIdx.x << 7;
  const int lr = lane >> 3, lc = lane & 7;

  f32x4 acc[4][4] = {};

  for (int kt = 0; kt < K; kt += 64) {
    #pragma unroll
    for (int it = 0; it < 4; ++it) {
      int r0 = (wave << 5) + (it << 3);
      int rr = r0 + lr;
      int gch = lc ^ (rr & 7);
      async_ld16(A + (size_t)(row0 + rr) * K + kt + (gch << 3), sA + (r0 << 6));
      async_ld16(W + (size_t)(col0 + rr) * K + kt + (gch << 3), sB + (r0 << 6));
    }
    __syncthreads();
    #pragma unroll
    for (int kk = 0; kk < 2; ++kk) {
      bf16x8 af[4];
      #pragma unroll
      for (int i = 0; i < 4; ++i) {
        int m = (wm << 6) + (i << 4) + l16;
        af[i] = *(const bf16x8*)&sA[(m << 6) + ((((kk << 2) + quad) ^ (l16 & 7)) << 3)];
      }
      #pragma unroll
      for (int j = 0; j < 4; ++j) {
        int n = (wn << 6) + (j << 4) + l16;
        bf16x8 bfr = *(const bf16x8*)&sB[(n << 6) + ((((kk << 2) + quad) ^ (l16 & 7)) << 3)];
        #pragma unroll
        for (int i = 0; i < 4; ++i)
          acc[i][j] = __builtin_amdgcn_mfma_f32_16x16x32_bf16(af[i], bfr, acc[i][j], 0, 0, 0);
      }
    }
    __syncthreads();
  }

  // epilogue: wave-private 64x36 f32 LDS tile, 2 passes of 32 cols
  float* ct = (float*)ldsraw + wave * (64 * 36);
  #pragma unroll
  for (int p = 0; p < 2; ++p) {
    #pragma unroll
    for (int i = 0; i < 4; ++i)
      #pragma unroll
      for (int r = 0; r < 4; ++r) {
        int row = (i << 4) + (quad << 2) + r;
        ct[row * 36 + l16]      = acc[i][(p << 1) + 0][r];
        ct[row * 36 + 16 + l16] = acc[i][(p << 1) + 1][r];
      }
    float4 sS = make_float4(0.f, 0.f, 0.f, 0.f);
    float4 sD = make_float4(0.f, 0.f, 0.f, 0.f);
    // same-wave LDS write->read ordering handled by compiler waitcnt
    #pragma unroll
    for (int it2 = 0; it2 < 8; ++it2) {
      int row = (it2 << 3) + lr;
      int c4 = lc << 2;
      float4 v = *(const float4*)&ct[row * 36 + c4];
      int gcol = col0 + (wn << 6) + (p << 5) + c4;
      size_t gidx = (size_t)(row0 + (wm << 6) + row) * Nn + gcol;
      if (FLAGS & GF_ALS) {
        float asv = b2f(asp[row0 + (wm << 6) + row]);
        float adv = b2f(adp[row0 + (wm << 6) + row]);
        sS.x += asv * v.x; sS.y += asv * v.y; sS.z += asv * v.z; sS.w += asv * v.w;
        sD.x += adv * v.x; sD.y += adv * v.y; sD.z += adv * v.z; sD.w += adv * v.w;
      }
      if (bias) {
        float4 bv = load4(bias + gcol);
        v.x += bv.x; v.y += bv.y; v.z += bv.z; v.w += bv.w;
      }
      if (FLAGS & GF_GELU) {
        v.x = gelu_f(v.x); v.y = gelu_f(v.y); v.z = gelu_f(v.z); v.w = gelu_f(v.w);
      }
      if (FLAGS & GF_RES) {
        float4 rv = *(const float4*)&res[gidx];
        v.x += rv.x; v.y += rv.y; v.z += rv.z; v.w += rv.w;
      }
      storev(C + gidx, v);
      if (FLAGS & GF_MIR) store4(C2 + gidx, v);
    }
    if (FLAGS & GF_ALS) {
      #pragma unroll
      for (int o = 8; o < 64; o <<= 1) {
        sS.x += __shfl_xor(sS.x, o); sS.y += __shfl_xor(sS.y, o);
        sS.z += __shfl_xor(sS.z, o); sS.w += __shfl_xor(sS.w, o);
        sD.x += __shfl_xor(sD.x, o); sD.y += __shfl_xor(sD.y, o);
        sD.z += __shfl_xor(sD.z, o); sD.w += __shfl_xor(sD.w, o);
      }
      if (lr == 0) {
        int node = col0 + (wn << 6) + (p << 5) + (lc << 2);
        int hd2 = blockIdx.y >> 1;
        int slice = ((blockIdx.y & 1) << 1) | wm;
        *(float4*)&alsp[(size_t)((slice << 3) + hd2) * Nn + node] = sS;
        *(float4*)&alsp[(size_t)((slice << 3) + 4 + hd2) * Nn + node] = sD;
      }
    }
  }
}

// ---------------------------------------------------------------------------
// gemm_rln: residual GEMM with fused epilogue.  C-tile = 32 rows x 256 cols
// (full row), grid = M/32 blocks (36 KB LDS -> 4 blocks/CU for latency hiding).
// h += A*W^T + bias (f32, in/out);
// POOL=false: tn = LN(h_new) (bf16)
// POOL=true:  hbm = bf16(h_new) mirror; logits[row] = dot(h_new_row, pw)+pbp[0]
// Nn fixed = 256, K%64==0.
// ---------------------------------------------------------------------------
template<bool POOL>
__global__ __launch_bounds__(256) void gemm_rln(
    const bf16* __restrict__ A, const bf16* __restrict__ W,
    const bf16* __restrict__ bias, float* __restrict__ h,
    bf16* __restrict__ tn, const bf16* __restrict__ lng,
    const bf16* __restrict__ lnb, int K,
    bf16* __restrict__ hbm, const bf16* __restrict__ pw,
    const bf16* __restrict__ pbp, float* __restrict__ logits)
{
  __shared__ __align__(16) char ldsraw[36864];   // staging 36 KB | epilogue 32.5 KB
  unsigned short* sA = (unsigned short*)ldsraw;  // 32 x 64 shorts
  unsigned short* sB = sA + 32 * 64;             // 256 x 64 shorts
  const int tid = threadIdx.x;
  const int wave = tid >> 6, lane = tid & 63;
  const int quad = lane >> 4, l16 = lane & 15;
  const int row0 = blockIdx.x << 5;
  const int lr = lane >> 3, lc = lane & 7;

  f32x4 acc[2][4] = {};

  for (int kt = 0; kt < K; kt += 64) {
    {
      int rr = (wave << 3) + lr;
      int gch = lc ^ (rr & 7);
      async_ld16(A + (size_t)(row0 + rr) * K + kt + (gch << 3), sA + (wave << 9));
    }
    #pragma unroll
    for (int it = 0; it < 8; ++it) {
      int r0 = (wave << 6) + (it << 3);
      int rr = r0 + lr;
      int gch = lc ^ (rr & 7);
      async_ld16(W + (size_t)rr * K + kt + (gch << 3), sB + (r0 << 6));
    }
    __syncthreads();
    #pragma unroll
    for (int kk = 0; kk < 2; ++kk) {
      bf16x8 af[2];
      #pragma unroll
      for (int i = 0; i < 2; ++i) {
        int m = (i << 4) + l16;
        af[i] = *(const bf16x8*)&sA[(m << 6) + ((((kk << 2) + quad) ^ (l16 & 7)) << 3)];
      }
      #pragma unroll
      for (int j = 0; j < 4; ++j) {
        int n = (wave << 6) + (j << 4) + l16;
        bf16x8 bfr = *(const bf16x8*)&sB[(n << 6) + ((((kk << 2) + quad) ^ (l16 & 7)) << 3)];
        #pragma unroll
        for (int i = 0; i < 2; ++i)
          acc[i][j] = __builtin_amdgcn_mfma_f32_16x16x32_bf16(af[i], bfr, acc[i][j], 0, 0, 0);
      }
    }
    __syncthreads();
  }

  // scatter acc into shared 32 x 260 f32 tile (full rows in one block)
  float* ct = (float*)ldsraw;
  #pragma unroll
  for (int j = 0; j < 4; ++j) {
    int col = (wave << 6) + (j << 4) + l16;
    #pragma unroll
    for (int i = 0; i < 2; ++i)
      #pragma unroll
      for (int r = 0; r < 4; ++r)
        ct[((i << 4) + (quad << 2) + r) * 260 + col] = acc[i][j][r];
  }
  __syncthreads();

  // thread = (row, eighth): 8 threads per row, 32 cols each, all in regs
  const int row = tid >> 3, q = tid & 7;
  const int c0 = q << 5;
  size_t gr = (size_t)(row0 + row) * 256 + c0;
  float4 v[8];
  float s1 = 0.f;
  #pragma unroll
  for (int k = 0; k < 8; ++k) {
    float4 cv = *(const float4*)&ct[row * 260 + c0 + (k << 2)];
    float4 bv = load4(bias + c0 + (k << 2));
    float4 rv = *(const float4*)&h[gr + (k << 2)];
    v[k].x = cv.x + bv.x + rv.x;
    v[k].y = cv.y + bv.y + rv.y;
    v[k].z = cv.z + bv.z + rv.z;
    v[k].w = cv.w + bv.w + rv.w;
    *(float4*)&h[gr + (k << 2)] = v[k];
    if (POOL) store4(hbm + gr + (k << 2), v[k]);
    s1 += v[k].x + v[k].y + v[k].z + v[k].w;
  }
  if (POOL) {
    float dp = 0.f;
    #pragma unroll
    for (int k = 0; k < 8; ++k) {
      float4 wv = load4(pw + c0 + (k << 2));
      dp += v[k].x * wv.x + v[k].y * wv.y + v[k].z * wv.z + v[k].w * wv.w;
    }
    dp += __shfl_xor(dp, 1); dp += __shfl_xor(dp, 2); dp += __shfl_xor(dp, 4);
    if (q == 0) logits[row0 + row] = dp + b2f(pbp[0]);
  } else {
    s1 += __shfl_xor(s1, 1); s1 += __shfl_xor(s1, 2); s1 += __shfl_xor(s1, 4);
    float mean = s1 * (1.0f / 256.0f);
    float s2 = 0.f;
    #pragma unroll
    for (int k = 0; k < 8; ++k) {
      float dx = v[k].x - mean, dy = v[k].y - mean, dz = v[k].z - mean, dw = v[k].w - mean;
      s2 += dx * dx + dy * dy + dz * dz + dw * dw;
    }
    s2 += __shfl_xor(s2, 1); s2 += __shfl_xor(s2, 2); s2 += __shfl_xor(s2, 4);
    float rstd = rsqrtf(s2 * (1.0f / 256.0f) + 1e-5f);
    #pragma unroll
    for (int k = 0; k < 8; ++k) {
      float4 gv = load4(lng + c0 + (k << 2));
      float4 bv2 = load4(lnb + c0 + (k << 2));
      float4 y;
      y.x = (v[k].x - mean) * rstd * gv.x + bv2.x;
      y.y = (v[k].y - mean) * rstd * gv.y + bv2.y;
      y.z = (v[k].z - mean) * rstd * gv.z + bv2.z;
      y.w = (v[k].w - mean) * rstd * gv.w + bv2.w;
      store4(tn + gr + (k << 2), y);
    }
  }
}

// ---------------------------------------------------------------------------
// gemm_pol: back-to-back policy head.  out = gelu(A@W1^T + b1) @ W2^T + b2.
// 32 rows/block; intermediate kept in LDS (bf16, XOR-swizzled for MFMA reads).
// ---------------------------------------------------------------------------
__global__ __launch_bounds__(256) void gemm_pol(
    const bf16* __restrict__ A, const bf16* __restrict__ W1,
    const bf16* __restrict__ b1, const bf16* __restrict__ W2,
    const bf16* __restrict__ b2p, bf16* __restrict__ out)
{
  __shared__ __align__(16) char ldsraw[36864];
  __shared__ __align__(16) unsigned short inter[4][2048];   // 4 kt-chunks x 32x64
  unsigned short* sA = (unsigned short*)ldsraw;
  unsigned short* sB = sA + 32 * 64;
  const int tid = threadIdx.x;
  const int wave = tid >> 6, lane = tid & 63;
  const int quad = lane >> 4, l16 = lane & 15;
  const int row0 = blockIdx.x << 5;
  const int lr = lane >> 3, lc = lane & 7;
  float* ct = (float*)ldsraw;
  const int row = tid >> 3, q = tid & 7;
  const int c0 = q << 5;

  // pass 1: T = gelu(A @ W1^T + b1)  -> inter (bf16, swizzled)
  {
    f32x4 acc[2][4] = {};
    for (int kt = 0; kt < 256; kt += 64) {
      { int rr = (wave << 3) + lr; int gch = lc ^ (rr & 7);
        async_ld16(A + (size_t)(row0 + rr) * 256 + kt + (gch << 3), sA + (wave << 9)); }
      #pragma unroll
      for (int it = 0; it < 8; ++it) {
        int r0 = (wave << 6) + (it << 3); int rr = r0 + lr; int gch = lc ^ (rr & 7);
        async_ld16(W1 + (size_t)rr * 256 + kt + (gch << 3), sB + (r0 << 6));
      }
      __syncthreads();
      #pragma unroll
      for (int kk = 0; kk < 2; ++kk) {
        bf16x8 af[2];
        #pragma unroll
        for (int i = 0; i < 2; ++i) {
          int m = (i << 4) + l16;
          af[i] = *(const bf16x8*)&sA[(m << 6) + ((((kk << 2) + quad) ^ (l16 & 7)) << 3)];
        }
        #pragma unroll
        for (int j = 0; j < 4; ++j) {
          int n = (wave << 6) + (j << 4) + l16;
          bf16x8 bfr = *(const bf16x8*)&sB[(n << 6) + ((((kk << 2) + quad) ^ (l16 & 7)) << 3)];
          #pragma unroll
          for (int i = 0; i < 2; ++i)
            acc[i][j] = __builtin_amdgcn_mfma_f32_16x16x32_bf16(af[i], bfr, acc[i][j], 0, 0, 0);
        }
      }
      __syncthreads();
    }
    #pragma unroll
    for (int j = 0; j < 4; ++j) {
      int col = (wave << 6) + (j << 4) + l16;
      #pragma unroll
      for (int i = 0; i < 2; ++i)
        #pragma unroll
        for (int r = 0; r < 4; ++r)
          ct[((i << 4) + (quad << 2) + r) * 260 + col] = acc[i][j][r];
    }
    __syncthreads();
    #pragma unroll
    for (int k = 0; k < 8; ++k) {
      int col = c0 + (k << 2);
      float4 cv = *(const float4*)&ct[row * 260 + col];
      float4 bv = load4(b1 + col);
      unsigned short u[4] = { f2us(gelu_f(cv.x + bv.x)), f2us(gelu_f(cv.y + bv.y)),
                              f2us(gelu_f(cv.z + bv.z)), f2us(gelu_f(cv.w + bv.w)) };
      int ktb = col >> 6, cc = col & 63, ch = cc >> 3, wc = cc & 7;
      *(ushort4*)&inter[ktb][(row << 6) + ((ch ^ (row & 7)) << 3) + wc] = *(ushort4*)u;
    }
  }
  __syncthreads();

  // pass 2: out = T @ W2^T + b2
  {
    f32x4 acc[2][4] = {};
    #pragma unroll
    for (int kt2 = 0; kt2 < 4; ++kt2) {
      #pragma unroll
      for (int it = 0; it < 8; ++it) {
        int r0 = (wave << 6) + (it << 3); int rr = r0 + lr; int gch = lc ^ (rr & 7);
        async_ld16(W2 + (size_t)rr * 256 + (kt2 << 6) + (gch << 3), sB + (r0 << 6));
      }
      __syncthreads();
      #pragma unroll
      for (int kk = 0; kk < 2; ++kk) {
        bf16x8 af[2];
        #pragma unroll
        for (int i = 0; i < 2; ++i) {
          int m = (i << 4) + l16;
          af[i] = *(const bf16x8*)&inter[kt2][(m << 6) + ((((kk << 2) + quad) ^ (l16 & 7)) << 3)];
        }
        #pragma unroll
        for (int j = 0; j < 4; ++j) {
          int n = (wave << 6) + (j << 4) + l16;
          bf16x8 bfr = *(const bf16x8*)&sB[(n << 6) + ((((kk << 2) + quad) ^ (l16 & 7)) << 3)];
          #pragma unroll
          for (int i = 0; i < 2; ++i)
            acc[i][j] = __builtin_amdgcn_mfma_f32_16x16x32_bf16(af[i], bfr, acc[i][j], 0, 0, 0);
        }
      }
      __syncthreads();
    }
    #pragma unroll
    for (int j = 0; j < 4; ++j) {
      int col = (wave << 6) + (j << 4) + l16;
      #pragma unroll
      for (int i = 0; i < 2; ++i)
        #pragma unroll
        for (int r = 0; r < 4; ++r)
          ct[((i << 4) + (quad << 2) + r) * 260 + col] = acc[i][j][r];
    }
    __syncthreads();
    #pragma unroll
    for (int k = 0; k < 8; ++k) {
      int col = c0 + (k << 2);
      float4 cv = *(const float4*)&ct[row * 260 + col];
      float4 bv = load4(b2p + col);
      store4(out + (size_t)(row0 + row) * 256 + col,
             make_float4(cv.x + bv.x, cv.y + bv.y, cv.z + bv.z, cv.w + bv.w));
    }
  }
}

// ---------------------------------------------------------------------------
// heads_fused: value + uncertainty heads in one kernel (32 graphs/block).
// value = tanh(gelu(g_rep@vw1^T+vb1) @ vw2 + vb2)
// unc   = softplus(gelu(g_rep@uw1^T+ub1) @ uw2 + ub2)
// ---------------------------------------------------------------------------
__global__ __launch_bounds__(256) void heads_fused(
    const bf16* __restrict__ g_rep,
    const bf16* __restrict__ vw1, const bf16* __restrict__ vb1,
    const bf16* __restrict__ vw2, const bf16* __restrict__ vb2,
    const bf16* __restrict__ uw1, const bf16* __restrict__ ub1,
    const bf16* __restrict__ uw2, const bf16* __restrict__ ub2,
    bf16* __restrict__ o_val, bf16* __restrict__ o_unc)
{
  __shared__ __align__(16) char ldsraw[36864];
  unsigned short* sA = (unsigned short*)ldsraw;
  unsigned short* sB = sA + 32 * 64;
  const int tid = threadIdx.x;
  const int wave = tid >> 6, lane = tid & 63;
  const int quad = lane >> 4, l16 = lane & 15;
  const int row0 = blockIdx.x << 5;
  const int lr = lane >> 3, lc = lane & 7;
  float* ct = (float*)ldsraw;
  const int row = tid >> 3, q = tid & 7;
  const int c0 = q << 5;

  // ---- value head (Nn=256) ----
  {
    f32x4 acc[2][4] = {};
    for (int kt = 0; kt < 256; kt += 64) {
      { int rr = (wave << 3) + lr; int gch = lc ^ (rr & 7);
        async_ld16(g_rep + (size_t)(row0 + rr) * 256 + kt + (gch << 3), sA + (wave << 9)); }
      #pragma unroll
      for (int it = 0; it < 8; ++it) {
        int r0 = (wave << 6) + (it << 3); int rr = r0 + lr; int gch = lc ^ (rr & 7);
        async_ld16(vw1 + (size_t)rr * 256 + kt + (gch << 3), sB + (r0 << 6));
      }
      __syncthreads();
      #pragma unroll
      for (int kk = 0; kk < 2; ++kk) {
        bf16x8 af[2];
        #pragma unroll
        for (int i = 0; i < 2; ++i) {
          int m = (i << 4) + l16;
          af[i] = *(const bf16x8*)&sA[(m << 6) + ((((kk << 2) + quad) ^ (l16 & 7)) << 3)];
        }
        #pragma unroll
        for (int j = 0; j < 4; ++j) {
          int n = (wave << 6) + (j << 4) + l16;
          bf16x8 bfr = *(const bf16x8*)&sB[(n << 6) + ((((kk << 2) + quad) ^ (l16 & 7)) << 3)];
          #pragma unroll
          for (int i = 0; i < 2; ++i)
            acc[i][j] = __builtin_amdgcn_mfma_f32_16x16x32_bf16(af[i], bfr, acc[i][j], 0, 0, 0);
        }
      }
      __syncthreads();
    }
    #pragma unroll
    for (int j = 0; j < 4; ++j) {
      int col = (wave << 6) + (j << 4) + l16;
      #pragma unroll
      for (int i = 0; i < 2; ++i)
        #pragma unroll
        for (int r = 0; r < 4; ++r)
          ct[((i << 4) + (quad << 2) + r) * 260 + col] = acc[i][j][r];
    }
    __syncthreads();
    float dp = 0.f;
    #pragma unroll
    for (int k = 0; k < 8; ++k) {
      float4 cv = *(const float4*)&ct[row * 260 + c0 + (k << 2)];
      float4 bv = load4(vb1 + c0 + (k << 2));
      float4 wv = load4(vw2 + c0 + (k << 2));
      dp += gelu_f(cv.x + bv.x) * wv.x + gelu_f(cv.y + bv.y) * wv.y
          + gelu_f(cv.z + bv.z) * wv.z + gelu_f(cv.w + bv.w) * wv.w;
    }
    dp += __shfl_xor(dp, 1); dp += __shfl_xor(dp, 2); dp += __shfl_xor(dp, 4);
    if (q == 0) o_val[row0 + row] = f2b(tanhf(dp + b2f(vb2[0])));
  }
  __syncthreads();

  // ---- uncertainty head (Nn=128; waves 0-1 own cols, others duplicate) ----
  {
    f32x4 acc[2][4] = {};
    for (int kt = 0; kt < 256; kt += 64) {
      { int rr = (wave << 3) + lr; int gch = lc ^ (rr & 7);
        async_ld16(g_rep + (size_t)(row0 + rr) * 256 + kt + (gch << 3), sA + (wave << 9)); }
      #pragma unroll
      for (int it = 0; it < 4; ++it) {
        int r0 = (wave << 5) + (it << 3); int rr = r0 + lr; int gch = lc ^ (rr & 7);
        async_ld16(uw1 + (size_t)rr * 256 + kt + (gch << 3), sB + (r0 << 6));
      }
      __syncthreads();
      #pragma unroll
      for (int kk = 0; kk < 2; ++kk) {
        bf16x8 af[2];
        #pragma unroll
        for (int i = 0; i < 2; ++i) {
          int m = (i << 4) + l16;
          af[i] = *(const bf16x8*)&sA[(m << 6) + ((((kk << 2) + quad) ^ (l16 & 7)) << 3)];
        }
        #pragma unroll
        for (int j = 0; j < 4; ++j) {
          int n = ((wave & 1) << 6) + (j << 4) + l16;
          bf16x8 bfr = *(const bf16x8*)&sB[(n << 6) + ((((kk << 2) + quad) ^ (l16 & 7)) << 3)];
          #pragma unroll
          for (int i = 0; i < 2; ++i)
            acc[i][j] = __builtin_amdgcn_mfma_f32_16x16x32_bf16(af[i], bfr, acc[i][j], 0, 0, 0);
        }
      }
      __syncthreads();
    }
    if (wave < 2) {
      #pragma unroll
      for (int j = 0; j < 4; ++j) {
        int col = (wave << 6) + (j << 4) + l16;
        #pragma unroll
        for (int i = 0; i < 2; ++i)
          #pragma unroll
          for (int r = 0; r < 4; ++r)
            ct[((i << 4) + (quad << 2) + r) * 260 + col] = acc[i][j][r];
      }
    }
    __syncthreads();
    float dp = 0.f;
    if (q < 4) {
      #pragma unroll
      for (int k = 0; k < 8; ++k) {
        float4 cv = *(const float4*)&ct[row * 260 + c0 + (k << 2)];
        float4 bv = load4(ub1 + c0 + (k << 2));
        float4 wv = load4(uw2 + c0 + (k << 2));
        dp += gelu_f(cv.x + bv.x) * wv.x + gelu_f(cv.y + bv.y) * wv.y
            + gelu_f(cv.z + bv.z) * wv.z + gelu_f(cv.w + bv.w) * wv.w;
      }
    }
    dp += __shfl_xor(dp, 1); dp += __shfl_xor(dp, 2); dp += __shfl_xor(dp, 4);
    if (q == 0) {
      float x = dp + b2f(ub2[0]);
      float sp = (x > 20.f) ? x : log1pf(expf(x));
      o_unc[row0 + row] = f2b(sp);
    }
  }
}

// ---------------------------------------------------------------------------
// CSR build over dst
// ---------------------------------------------------------------------------
__global__ void csr_count(const int* __restrict__ edst, int* __restrict__ cnt){
  int e = blockIdx.x * 256 + threadIdx.x;
  if (e < NE2) {
    int d = (e < NE) ? edst[e] : (e - NE);
    atomicAdd(&cnt[d], 1);
  }
}
__global__ __launch_bounds__(1024) void csr_scan(const int* __restrict__ cnt, int* __restrict__ off){
  __shared__ int ls[1024];
  int t = threadIdx.x;
  int base = t * 16;
  int loc[16]; int s = 0;
  #pragma unroll
  for (int j = 0; j < 16; ++j) { loc[j] = s; s += cnt[base + j]; }
  ls[t] = s;
  __syncthreads();
  for (int o = 1; o < 1024; o <<= 1) {
    int v = (t >= o) ? ls[t - o] : 0;
    __syncthreads();
    ls[t] += v;
    __syncthreads();
  }
  int pre = (t == 0) ? 0 : ls[t - 1];
  #pragma unroll
  for (int j = 0; j < 16; ++j) off[base + j] = pre + loc[j];
  if (t == 1023) off[N_NODES] = ls[1023];
}
__global__ void csr_fill(const int* __restrict__ edst, const int* __restrict__ off,
                         int* __restrict__ fillc, int* __restrict__ list){
  int e = blockIdx.x * 256 + threadIdx.x;
  if (e < NE2) {
    int d = (e < NE) ? edst[e] : (e - NE);
    int p = atomicAdd(&fillc[d], 1);
    list[off[d] + p] = e;
  }
}

// ---------------------------------------------------------------------------
// GAT per-(graph,head) block.  hpT_g [1024 ch][16384 nodes] is read DIRECTLY
// from global in the MFMA loop (B-fragments = 8 consecutive nodes for a fixed
// channel = contiguous 16B in hpT_g; data is L2/L3-resident and each fragment
// is used exactly once, so LDS staging added no reuse — dropping it cuts LDS
// 50->18 KB and lifts occupancy 3->8 blocks/CU).
// ---------------------------------------------------------------------------
#define ALF_S 68

__device__ __forceinline__ bf16x8 pack8(const float* v, float scale){
  unsigned short u[8];
  #pragma unroll
  for (int t = 0; t < 8; ++t) u[t] = f2us(v[t] * scale);
  bf16x8 r; __builtin_memcpy(&r, u, 16); return r;
}

__global__ __launch_bounds__(256) void gat_graph2(
    const int* __restrict__ esrc, const bf16* __restrict__ hpT_g,
    const int* __restrict__ off, const int* __restrict__ list,
    const float* __restrict__ alsp,
    bf16* __restrict__ msg4, int g0, int hn)
{
  __shared__ float alpha[64 * ALF_S];
  __shared__ float als[64], ald[64], dinv[64];

  const int hd = blockIdx.x & 3;
  const int lg = blockIdx.x >> 2;
  const int g  = g0 + lg;
  const int tid = threadIdx.x;
  const int wave = tid >> 6, lane = tid & 63;
  const int quad = lane >> 4, l16 = lane & 15;
  const int nd = tid >> 2;
  const int k4 = tid & 3;

  if (tid < 128) {
    int n2 = tid & 63;
    int sd = (tid >> 6) << 2;                 // 0 = als, 4 = ald
    float v = 0.f;
    #pragma unroll
    for (int sl = 0; sl < 4; ++sl)
      v += alsp[(size_t)((sl << 3) + sd + hd) * 16384 + (g << 6) + n2];
    if (sd) ald[n2] = v; else als[n2] = v;
  }
  #pragma unroll
  for (int idx = tid; idx < 64 * ALF_S; idx += 256) alpha[idx] = 0.f;
  __syncthreads();

  {
    int st = off[(g << 6) + nd];
    int deg = off[(g << 6) + nd + 1] - st;
    float ad = ald[nd];
    float mx = -1e30f;
    for (int e = k4; e < deg; e += 4) {
      int ed = list[st + e];
      int sl = ((ed < NE) ? esrc[ed] : (ed - NE)) - (g << 6);
      float v = als[sl] + ad;
      v = (v > 0.f) ? v : 0.2f * v;
      mx = fmaxf(mx, v);
    }
    mx = fmaxf(mx, __shfl_xor(mx, 1)); mx = fmaxf(mx, __shfl_xor(mx, 2));
    float den = 0.f;
    for (int e = k4; e < deg; e += 4) {
      int ed = list[st + e];
      int sl = ((ed < NE) ? esrc[ed] : (ed - NE)) - (g << 6);
      float v = als[sl] + ad;
      v = (v > 0.f) ? v : 0.2f * v;
      float w = __expf(v - mx);
      den += w;
      atomicAdd(&alpha[nd * ALF_S + sl], w);
    }
    den += __shfl_xor(den, 1); den += __shfl_xor(den, 2);
    if (k4 == 0) dinv[nd] = 1.0f / den;
  }
  __syncthreads();

  f32x4 acc[4][4] = {};
  #pragma unroll
  for (int kk = 0; kk < 2; ++kk) {
    bf16x8 af[4];
    #pragma unroll
    for (int i = 0; i < 4; ++i) {
      int m = (i << 4) + l16;
      const float* ap = &alpha[m * ALF_S + (kk << 5) + (quad << 3)];
      float av[8];
      float4 a0 = *(const float4*)ap, a1 = *(const float4*)(ap + 4);
      av[0]=a0.x; av[1]=a0.y; av[2]=a0.z; av[3]=a0.w;
      av[4]=a1.x; av[5]=a1.y; av[6]=a1.z; av[7]=a1.w;
      af[i] = pack8(av, dinv[m]);
    }
    #pragma unroll
    for (int j = 0; j < 4; ++j) {
      int c2 = (wave << 6) + (j << 4) + l16;          // channel within head
      int chunk = (kk << 2) + quad;                   // 8-node k-subchunk
      bf16x8 bfr = *(const bf16x8*)&hpT_g[(size_t)((hd << 8) + c2) * 16384 + (g << 6) + (chunk << 3)];
      #pragma unroll
      for (int i = 0; i < 4; ++i)
        acc[i][j] = __builtin_amdgcn_mfma_f32_16x16x32_bf16(af[i], bfr, acc[i][j], 0, 0, 0);
    }
  }

  #pragma unroll
  for (int j = 0; j < 4; ++j) {
    int col = (wave << 6) + (j << 4) + l16;
    #pragma unroll
    for (int i = 0; i < 4; ++i) {
      int rbase = (i << 4) + (quad << 2);
      #pragma unroll
      for (int r = 0; r < 4; ++r)
        msg4[((size_t)hd * hn + (lg << 6) + rbase + r) * 256 + col] = f2b(acc[i][j][r]);
    }
  }
}

// Head-mean + bias + LayerNorm + GELU + residual; writes f32 h + bf16 mirror hb.
// Optional second LN (lng/lnb/tno): tn = LN(h_new) for the following TF layer.
__global__ __launch_bounds__(256) void gat_epi(
    const bf16* __restrict__ msg4, int hn, int n0,
    const bf16* __restrict__ bias, const bf16* __restrict__ gg, const bf16* __restrict__ gb,
    float* __restrict__ h, bf16* __restrict__ hb,
    const bf16* __restrict__ lng, const bf16* __restrict__ lnb, bf16* __restrict__ tno)
{
  int nl = blockIdx.x * 4 + (threadIdx.x >> 6);
  int lane = threadIdx.x & 63;
  int c = lane * 4;
  float4 s = make_float4(0.f, 0.f, 0.f, 0.f);
  #pragma unroll
  for (int hd = 0; hd < 4; ++hd) {
    float4 m = load4(msg4 + ((size_t)hd * hn + nl) * 256 + c);
    s.x += m.x; s.y += m.y; s.z += m.z; s.w += m.w;
  }
  float4 bv = load4(bias + c);
  float ox = s.x * 0.25f + bv.x, oy = s.y * 0.25f + bv.y;
  float oz = s.z * 0.25f + bv.z, ow = s.w * 0.25f + bv.w;
  float mean = wave_sum(ox + oy + oz + ow) * (1.0f / 256.0f);
  float dx = ox - mean, dy = oy - mean, dz = oz - mean, dw = ow - mean;
  float var = wave_sum(dx*dx + dy*dy + dz*dz + dw*dw) * (1.0f / 256.0f);
  float r = rsqrtf(var + 1e-5f);
  float4 gv = load4(gg + c); float4 b2 = load4(gb + c);
  size_t base = ((size_t)(n0 + nl)) * 256 + c;
  float4 hv = load4(h + base);
  hv.x += gelu_f(dx * r * gv.x + b2.x);
  hv.y += gelu_f(dy * r * gv.y + b2.y);
  hv.z += gelu_f(dz * r * gv.z + b2.z);
  hv.w += gelu_f(dw * r * gv.w + b2.w);
  store4(h + base, hv);
  store4(hb + base, hv);
  if (lng) {
    float m2 = wave_sum(hv.x + hv.y + hv.z + hv.w) * (1.0f / 256.0f);
    float ex = hv.x - m2, ey = hv.y - m2, ez = hv.z - m2, ew = hv.w - m2;
    float v2 = wave_sum(ex*ex + ey*ey + ez*ez + ew*ew) * (1.0f / 256.0f);
    float r2 = rsqrtf(v2 + 1e-5f);
    float4 g2 = load4(lng + c); float4 bb = load4(lnb + c);
    store4(tno + base, make_float4(ex*r2*g2.x + bb.x, ey*r2*g2.y + bb.y,
                                   ez*r2*g2.z + bb.z, ew*r2*g2.w + bb.w));
  }
}

// ---------------------------------------------------------------------------
// LayerNorm: wave-per-row (4 rows/block), f32 in, bf16 out (fallback path)
// ---------------------------------------------------------------------------
__global__ __launch_bounds__(256) void ln_kernel(
    const float* __restrict__ x, bf16* __restrict__ y,
    const bf16* __restrict__ g, const bf16* __restrict__ b)
{
  int row = blockIdx.x * 4 + (threadIdx.x >> 6);
  int lane = threadIdx.x & 63;
  int c = lane * 4;
  float4 v = load4(x + (size_t)row * 256 + c);
  float mean = wave_sum(v.x + v.y + v.z + v.w) * (1.0f / 256.0f);
  float dx = v.x - mean, dy = v.y - mean, dz = v.z - mean, dw = v.w - mean;
  float var = wave_sum(dx*dx + dy*dy + dz*dz + dw*dw) * (1.0f / 256.0f);
  float r = rsqrtf(var + 1e-5f);
  float4 gv = load4(g + c); float4 bv = load4(b + c);
  store4(y + (size_t)row * 256 + c,
         make_float4(dx*r*gv.x + bv.x, dy*r*gv.y + bv.y, dz*r*gv.z + bv.z, dw*r*gv.w + bv.w));
}

// ---------------------------------------------------------------------------
// MFMA flash-style attention (unchanged)
// ---------------------------------------------------------------------------
#define VT_LDS 268
#define P_LDS  72

__global__ __launch_bounds__(256) void attn_mfma(
    const bf16* __restrict__ qkv, bf16* __restrict__ obuf)
{
  const int b  = blockIdx.x & 63;
  const int hh = blockIdx.x >> 6;
  __shared__ unsigned short VTs[32 * VT_LDS];
  __shared__ unsigned short Ps[4][64 * P_LDS];
  const int tid  = threadIdx.x;
  const int wave = tid >> 6, lane = tid & 63;
  const int quad = lane >> 4, l16 = lane & 15;

  {
    const bf16* vb = qkv + (size_t)(tid * 64 + b) * 768 + 512 + hh * 32;
    unsigned short vv[32];
    *(uint4*)&vv[0]  = *(const uint4*)(vb);
    *(uint4*)&vv[8]  = *(const uint4*)(vb + 8);
    *(uint4*)&vv[16] = *(const uint4*)(vb + 16);
    *(uint4*)&vv[24] = *(const uint4*)(vb + 24);
    #pragma unroll
    for (int d = 0; d < 32; ++d) VTs[d * VT_LDS + tid] = vv[d];
  }
  bf16x8 qf[4];
  #pragma unroll
  for (int i = 0; i < 4; ++i) {
    int s = (wave << 6) + (i << 4) + l16;
    qf[i] = *(const bf16x8*)(qkv + (size_t)(s * 64 + b) * 768 + hh * 32 + (quad << 3));
  }
  __syncthreads();

  const float scale = 0.17677669529663687f;
  f32x4 oacc[4][2] = {};
  float lsum[4][4] = {};
  unsigned short* Pw = &Ps[wave][0];

  for (int nt = 0; nt < 4; ++nt) {
    bf16x8 kf[4];
    #pragma unroll
    for (int j = 0; j < 4; ++j) {
      int t = (nt << 6) + (j << 4) + l16;
      kf[j] = *(const bf16x8*)(qkv + (size_t)(t * 64 + b) * 768 + 256 + hh * 32 + (quad << 3));
    }
    f32x4 zero = {0.f, 0.f, 0.f, 0.f};
    f32x4 sx[4][4];
    #pragma unroll
    for (int i = 0; i < 4; ++i)
      #pragma unroll
      for (int j = 0; j < 4; ++j)
        sx[i][j] = __builtin_amdgcn_mfma_f32_16x16x32_bf16(qf[i], kf[j], zero, 0, 0, 0);
    #pragma unroll
    for (int i = 0; i < 4; ++i) {
      #pragma unroll
      for (int r = 0; r < 4; ++r) {
        float p[4]; float rs = 0.f;
        #pragma unroll
        for (int j = 0; j < 4; ++j) {
          float sc = fminf(fmaxf(sx[i][j][r] * scale, -60.f), 60.f);
          p[j] = __expf(sc);
          rs += p[j];
        }
        #pragma unroll
        for (int o = 1; o < 16; o <<= 1) rs += __shfl_xor(rs, o);
        lsum[i][r] += rs;
        int row = (i << 4) + (quad << 2) + r;
        #pragma unroll
        for (int j = 0; j < 4; ++j)
          Pw[row * P_LDS + (j << 4) + l16] = f2us(p[j]);
      }
    }
    #pragma unroll
    for (int kk = 0; kk < 2; ++kk) {
      bf16x8 vf[2];
      #pragma unroll
      for (int j2 = 0; j2 < 2; ++j2)
        vf[j2] = *(const bf16x8*)&VTs[((j2 << 4) + l16) * VT_LDS + (nt << 6) + (kk << 5) + (quad << 3)];
      #pragma unroll
      for (int i2 = 0; i2 < 4; ++i2) {
        bf16x8 pf = *(const bf16x8*)&Pw[((i2 << 4) + l16) * P_LDS + (kk << 5) + (quad << 3)];
        #pragma unroll
        for (int j2 = 0; j2 < 2; ++j2)
          oacc[i2][j2] = __builtin_amdgcn_mfma_f32_16x16x32_bf16(pf, vf[j2], oacc[i2][j2], 0, 0, 0);
      }
    }
  }
  #pragma unroll
  for (int i = 0; i < 4; ++i) {
    #pragma unroll
    for (int r = 0; r < 4; ++r) {
      int srow = (wave << 6) + (i << 4) + (quad << 2) + r;
      float inv = 1.0f / lsum[i][r];
      #pragma unroll
      for (int j2 = 0; j2 < 2; ++j2)
        obuf[(size_t)(srow * 64 + b) * 256 + hh * 32 + (j2 << 4) + l16] = f2b(oacc[i][j2][r] * inv);
    }
  }
}

// ---------------------------------------------------------------------------
// Pooling (g_rep emitted bf16)
// ---------------------------------------------------------------------------
__global__ __launch_bounds__(1024) void pool_reduce(
    const float* __restrict__ logits, float* __restrict__ red)
{
  __shared__ float sm[16];
  int t = threadIdx.x;
  float m = -1e30f;
  for (int i = t; i < N_NODES; i += 1024) m = fmaxf(m, logits[i]);
  m = wave_max(m);
  if ((t & 63) == 0) sm[t >> 6] = m;
  __syncthreads();
  if (t == 0) { float mm = sm[0]; for (int i = 1; i < 16; ++i) mm = fmaxf(mm, sm[i]); sm[0] = mm; }
  __syncthreads();
  float gmax = sm[0];
  __syncthreads();
  float s = 0.f;
  for (int i = t; i < N_NODES; i += 1024) s += expf(logits[i] - gmax);
  s = wave_sum(s);
  if ((t & 63) == 0) sm[t >> 6] = s;
  __syncthreads();
  if (t == 0) { float ss = 0.f; for (int i = 0; i < 16; ++i) ss += sm[i]; red[0] = gmax; red[1] = 1.0f / ss; }
}
__global__ __launch_bounds__(256) void pool_grep(
    const float* __restrict__ h, const float* __restrict__ logits,
    const float* __restrict__ red, bf16* __restrict__ g_rep)
{
  __shared__ float w[64];
  int g = blockIdx.x; int tid = threadIdx.x;
  if (tid < 64) w[tid] = expf(logits[g * 64 + tid] - red[0]) * red[1];
  __syncthreads();
  float acc = 0.f;
  for (int nd = 0; nd < 64; ++nd) acc += h[((size_t)g * 64 + nd) * 256 + tid] * w[nd];
  g_rep[(size_t)g * 256 + tid] = f2b(acc);
}

// ---------------------------------------------------------------------------
extern "C" void kernel_launch(void* const* d_in, const int* in_sizes, int n_in,
                              void* d_out, int out_size, void* d_ws, size_t ws_size,
                              hipStream_t stream)
{
  (void)out_size;
  const int* eidx = (const int*)d_in[1];

  char* ws = (char*)d_ws;
  size_t wo = 0;
  auto alloc = [&](size_t bytes) -> char* {
    char* p = ws + wo; wo += (bytes + 255) & ~(size_t)255; return p;
  };
  int*   flags = (int*)alloc(256);
  int*   cnt   = (int*)alloc((size_t)N_NODES * 4);
  int*   fillc = (int*)alloc((size_t)N_NODES * 4);
  size_t zero_end = wo;

  bf16* conv[38] = {};
  static const int fidx[35] = {0,4,5,6,7,8,9,10,11,12,13,14,15,16,17,18,19,
                               20,21,22,23,24,25,26,27,28,29,30,31,32,33,34,35,36,37};
  for (int j = 0; j < 35; ++j) {
    int idx = fidx[j];
    conv[idx] = (bf16*)alloc((size_t)in_sizes[idx] * 2);
  }
  float* h     = (float*)alloc((size_t)N_NODES * 256 * 4);
  bf16*  hb    = (bf16*) alloc((size_t)N_NODES * 256 * 2);   // bf16 mirror of h
  bf16*  big   = (bf16*) alloc((size_t)N_NODES * 1024 * 2);
  const int OUT_ELEMS = 256 + N_NODES * 256 + 256;
  bf16*  tn     = (bf16*)alloc((size_t)N_NODES * 256 * 2);   // adjacent to ostage
  bf16*  ostage = (bf16*)alloc((size_t)OUT_ELEMS * 2);
  int*   off   = (int*)alloc((size_t)(N_NODES + 1) * 4);
  int*   list  = (int*)alloc((size_t)NE2 * 4);
  float* logits= (float*)alloc((size_t)N_NODES * 4);
  float* redb  = (float*)alloc(256);
  bf16*  g_rep = (bf16*)alloc((size_t)256 * 256 * 2);
  float* alsp  = (float*)alloc((size_t)32 * N_NODES * 4);    // 4 slices x (s,d) x 4 heads
  size_t base_needed = wo;

  if (n_in != 38)                   { write_sentinel<<<1,256,0,stream>>>((bf16*)d_out, 4.f);  return; }
  if (in_sizes[0] != N_NODES * 128) { write_sentinel<<<1,256,0,stream>>>((bf16*)d_out, 8.f);  return; }
  if (in_sizes[1] != 2 * NE)        { write_sentinel<<<1,256,0,stream>>>((bf16*)d_out, 16.f); return; }
  if (ws_size < base_needed)        { write_sentinel<<<1,256,0,stream>>>((bf16*)d_out, 32.f); return; }

  size_t msg_bytes = (size_t)4 * N_NODES * 256 * 2;
  bf16* msg4; int halves;
  if (ws_size >= base_needed + msg_bytes + 256) {
    msg4 = (bf16*)alloc(msg_bytes); halves = 1;
  } else {
    msg4 = tn; halves = 2;
  }

  hipMemsetAsync(d_ws, 0, zero_end, stream);

  detect_dtype<<<256, 256, 0, stream>>>((const unsigned short*)d_in[0], 65536, flags);
  {
    ConvArgs ca;
    int cum = 0;
    for (int j = 0; j < 35; ++j) {
      int idx = fidx[j];
      ca.src[j] = d_in[idx];
      ca.dst[j] = (unsigned short*)conv[idx];
      ca.cumg[j] = cum;
      ca.n[j] = in_sizes[idx];
      cum += (in_sizes[idx] + 3) >> 2;
    }
    ca.cumg[35] = cum;
    conv_all4<<<(cum + 255) / 256, 256, 0, stream>>>(ca, flags);
  }
  const bf16 *xb = conv[0], *emb_w = conv[4], *emb_b = conv[5], *gat_w = conv[6],
             *gat_as = conv[7], *gat_ad = conv[8], *gat_b = conv[9], *gnn_g = conv[10],
             *gnn_beta = conv[11], *ln1_g = conv[12], *ln1_b = conv[13], *in_w = conv[14],
             *in_b = conv[15], *out_w = conv[16], *out_b = conv[17], *ln2_g = conv[18],
             *ln2_b = conv[19], *ff1_w = conv[20], *ff1_b = conv[21], *ff2_w = conv[22],
             *ff2_b = conv[23], *pool_w = conv[24], *pool_b = conv[25],
             *vw1 = conv[26], *vb1 = conv[27], *vw2 = conv[28], *vb2 = conv[29],
             *pw1 = conv[30], *pb1 = conv[31], *pw2 = conv[32], *pb2 = conv[33],
             *uw1 = conv[34], *ub1 = conv[35], *uw2 = conv[36], *ub2 = conv[37];

  bf16* qkv  = big;
  bf16* obuf = big + (size_t)N_NODES * 768;
  bf16* hpT_g = big;          // [1024 ch][16384 nodes] transposed GAT projection
  bf16* ffb  = big;
  bf16* o_val = ostage;
  bf16* o_pol = ostage + 256;
  bf16* o_unc = ostage + 256 + (size_t)N_NODES * 256;

  csr_count<<<(NE2 + 255) / 256, 256, 0, stream>>>(eidx + NE, cnt);
  csr_scan<<<1, 1024, 0, stream>>>(cnt, off);
  csr_fill<<<(NE2 + 255) / 256, 256, 0, stream>>>(eidx + NE, off, fillc, list);

  // Embedding: h (f32) + hb (bf16 mirror)
  gemm2<float, GF_MIR><<<dim3(2, 128), 256, 0, stream>>>(
      xb, emb_w, emb_b, nullptr, h, hb, N_NODES, 256, 128,
      nullptr, nullptr, nullptr);

  const int gph = 256 / halves;
  const int hn  = N_NODES / halves;
  for (int l = 0; l < 8; ++l) {
    // transposed projection: hpT = gat_w[l] @ hb^T, [1024][16384];
    // epilogue also emits als/ald partial slices into alsp.
    gemm2<bf16, GF_ALS><<<dim3(128, 8), 256, 0, stream>>>(
        gat_w + (size_t)l * 1024 * 256, hb, nullptr, nullptr, hpT_g, nullptr,
        1024, N_NODES, 256, gat_as + l * 1024, gat_ad + l * 1024, alsp);
    const bf16* lng = (l == 7 && halves == 1) ? ln1_g : nullptr;
    const bf16* lnb = (l == 7 && halves == 1) ? ln1_b : nullptr;
    for (int ph = 0; ph < halves; ++ph) {
      gat_graph2<<<gph * 4, 256, 0, stream>>>(eidx, hpT_g, off, list, alsp,
          msg4, ph * gph, hn);
      gat_epi<<<hn / 4, 256, 0, stream>>>(msg4, hn, ph * hn,
          gat_b + l * 256, gnn_g + l * 256, gnn_beta + l * 256, h, hb,
          lng, lnb, tn);
    }
  }
  if (halves == 2)
    ln_kernel<<<N_NODES / 4, 256, 0, stream>>>(h, tn, ln1_g, ln1_b);

  for (int l = 0; l < 6; ++l) {
    // tn already holds LN1(h) (from gat_epi l=7 or previous layer's fused ff2)
    gemm2<bf16, 0><<<dim3(6, 128), 256, 0, stream>>>(
        tn, in_w + (size_t)l * 768 * 256, in_b + l * 768, nullptr, qkv, nullptr, N_NODES, 768, 256,
        nullptr, nullptr, nullptr);
    attn_mfma<<<512, 256, 0, stream>>>(qkv, obuf);
    // h += attnout @ out_w^T + out_b ; tn = LN2(h)
    gemm_rln<false><<<N_NODES / 32, 256, 0, stream>>>(
        obuf, out_w + (size_t)l * 256 * 256, out_b + l * 256, h, tn,
        ln2_g + l * 256, ln2_b + l * 256, 256,
        nullptr, nullptr, nullptr, nullptr);
    gemm2<bf16, GF_GELU><<<dim3(8, 128), 256, 0, stream>>>(
        tn, ff1_w + (size_t)l * 1024 * 256, ff1_b + l * 1024, nullptr, ffb, nullptr, N_NODES, 1024, 256,
        nullptr, nullptr, nullptr);
    if (l < 5)
      // h += ffb @ ff2_w^T + ff2_b ; tn = LN1[l+1](h)
      gemm_rln<false><<<N_NODES / 32, 256, 0, stream>>>(
          ffb, ff2_w + (size_t)l * 256 * 1024, ff2_b + l * 256, h, tn,
          ln1_g + (l + 1) * 256, ln1_b + (l + 1) * 256, 1024,
          nullptr, nullptr, nullptr, nullptr);
    else
      // h += ffb @ ff2_w^T + ff2_b ; hb mirror ; logits = h @ pool_w + pb
      gemm_rln<true><<<N_NODES / 32, 256, 0, stream>>>(
          ffb, ff2_w + (size_t)l * 256 * 1024, ff2_b + l * 256, h, nullptr,
          nullptr, nullptr, 1024,
          hb, pool_w, pool_b, logits);
  }

  pool_reduce<<<1, 1024, 0, stream>>>(logits, redb);
  pool_grep<<<256, 256, 0, stream>>>(h, logits, redb, g_rep);
  heads_fused<<<8, 256, 0, stream>>>(
      g_rep, vw1, vb1, vw2, vb2, uw1, ub1, uw2, ub2, o_val, o_unc);
  gemm_pol<<<N_NODES / 32, 256, 0, stream>>>(hb, pw1, pb1, pw2, pb2, o_pol);

  emit_out<<<(OUT_ELEMS + 255) / 256, 256, 0, stream>>>(
      (const unsigned short*)ostage, d_out, OUT_ELEMS, flags);
}

// Round 10
// 1464.983 us; speedup vs baseline: 1.0936x; 1.0936x over previous
//
#include <hip/hip_runtime.h>
#include <hip/hip_bf16.h>

typedef __hip_bfloat16 bf16;
typedef __bf16 bf16x8 __attribute__((ext_vector_type(8)));
typedef float  f32x4  __attribute__((ext_vector_type(4)));

#define N_NODES 16384
#define HDIM    256
#define NE      131072
#define NE2     147456   // NE + N self loops

__device__ __forceinline__ float b2f(bf16 v){ return __bfloat162float(v); }
__device__ __forceinline__ bf16  f2b(float v){ return __float2bfloat16(v); }
__device__ __forceinline__ float us2f(unsigned short u){
  union { unsigned int i; float f; } c; c.i = ((unsigned int)u) << 16; return c.f;
}
__device__ __forceinline__ unsigned short f2us(float f){
  bf16 h = __float2bfloat16(f);
  unsigned short u; __builtin_memcpy(&u, &h, 2); return u;
}
__device__ __forceinline__ float gelu_f(float x){
  return 0.5f * x * (1.0f + erff(x * 0.7071067811865476f));
}
__device__ __forceinline__ float wave_sum(float v){
  #pragma unroll
  for (int o = 32; o > 0; o >>= 1) v += __shfl_xor(v, o);
  return v;
}
__device__ __forceinline__ float wave_max(float v){
  #pragma unroll
  for (int o = 32; o > 0; o >>= 1) v = fmaxf(v, __shfl_xor(v, o));
  return v;
}

__device__ __forceinline__ float4 load4(const float* p){ return *(const float4*)p; }
__device__ __forceinline__ float4 load4(const bf16* p){
  ushort4 u = *(const ushort4*)p;
  return make_float4(us2f(u.x), us2f(u.y), us2f(u.z), us2f(u.w));
}
__device__ __forceinline__ void store4(float* p, float4 v){ *(float4*)p = v; }
__device__ __forceinline__ void store4(bf16* p, float4 v){
  ushort4 u = make_ushort4(f2us(v.x), f2us(v.y), f2us(v.z), f2us(v.w));
  *(ushort4*)p = u;
}
__device__ __forceinline__ void storev(float* p, float4 v){ *(float4*)p = v; }
__device__ __forceinline__ void storev(bf16*  p, float4 v){ store4(p, v); }

// async 16B/lane global -> LDS (lds dest = wave-uniform base + lane*16)
__device__ __forceinline__ void async_ld16(const bf16* g, unsigned short* l){
  __builtin_amdgcn_global_load_lds(
      (const __attribute__((address_space(1))) void*)g,
      (__attribute__((address_space(3))) void*)l, 16, 0, 0);
}

// ---------------------------------------------------------------------------
// dtype detection + normalization.  flags[1] = input-is-f32
// ---------------------------------------------------------------------------
__global__ void detect_dtype(const unsigned short* __restrict__ x, int n, int* __restrict__ flags){
  int i = blockIdx.x * 256 + threadIdx.x;
  if (i < n) {
    unsigned short u = x[i];
    if ((u & 0x7F80) == 0x7F80) atomicOr(&flags[1], 1);
  }
}
struct ConvArgs {
  const void* src[35];
  unsigned short* dst[35];
  int cumg[36];
  int n[35];
};
__global__ void conv_all4(ConvArgs a, const int* __restrict__ flags){
  int gi = blockIdx.x * 256 + threadIdx.x;
  if (gi >= a.cumg[35]) return;
  int lo = 0, hi = 34;
  while (lo < hi) { int mid = (lo + hi + 1) >> 1; if (gi >= a.cumg[mid]) lo = mid; else hi = mid - 1; }
  int e0 = (gi - a.cumg[lo]) << 2;
  int n = a.n[lo];
  unsigned short* d = a.dst[lo];
  if (flags[1]) {
    const float* s = (const float*)a.src[lo];
    if (e0 + 4 <= n) {
      float4 v = *(const float4*)(s + e0);
      *(ushort4*)(d + e0) = make_ushort4(f2us(v.x), f2us(v.y), f2us(v.z), f2us(v.w));
    } else {
      for (int t = 0; t < n - e0; ++t) d[e0 + t] = f2us(s[e0 + t]);
    }
  } else {
    const unsigned short* s = (const unsigned short*)a.src[lo];
    if (e0 + 4 <= n) *(ushort4*)(d + e0) = *(const ushort4*)(s + e0);
    else for (int t = 0; t < n - e0; ++t) d[e0 + t] = s[e0 + t];
  }
}
__global__ void emit_out(const unsigned short* __restrict__ stage, void* __restrict__ out,
                         int n, const int* __restrict__ flags){
  int i = blockIdx.x * 256 + threadIdx.x;
  if (i >= n) return;
  if (flags[1]) ((float*)out)[i] = us2f(stage[i]);
  else          ((unsigned short*)out)[i] = stage[i];
}
__global__ void write_sentinel(bf16* out, float v){ out[threadIdx.x] = f2b(v); }

// ---------------------------------------------------------------------------
// gemm2: MFMA bf16 NT GEMM with async global->LDS staging (BK=64, XOR swizzle)
// and LDS-transposed vectorized epilogue. C = A[M,K] * W[Nn,K]^T (+bias)...
// FLAGS: 1 = gelu, 2 = residual add (res f32), 4 = also store bf16 mirror C2,
//        8 = GAT als/ald fused epilogue.
// M%128==0, Nn%128==0, K%64==0.
// NOTE: XCD blockIdx swizzle measured HARMFUL here (R7: +60% on gemm2 —
// operands are L2/L3-resident, no HBM win available). Natural order kept.
// ---------------------------------------------------------------------------
#define GF_GELU 1
#define GF_RES  2
#define GF_MIR  4
#define GF_ALS  8

template<typename TO, int FLAGS>
__global__ __launch_bounds__(256) void gemm2(
    const bf16* __restrict__ A, const bf16* __restrict__ W,
    const bf16* __restrict__ bias, const float* __restrict__ res,
    TO* __restrict__ C, bf16* __restrict__ C2, int M, int Nn, int K,
    const bf16* __restrict__ asp, const bf16* __restrict__ adp,
    float* __restrict__ alsp)
{
  __shared__ __align__(16) char ldsraw[36864];   // staging 32 KB | epilogue 36 KB
  unsigned short* sA = (unsigned short*)ldsraw;  // 128 rows x 64 shorts
  unsigned short* sB = sA + 128 * 64;
  const int tid = threadIdx.x;
  const int wave = tid >> 6, lane = tid & 63;
  const int quad = lane >> 4, l16 = lane & 15;
  const int wm = wave & 1, wn = wave >> 1;
  const int row0 = blockIdx.y << 7, col0 = blockIdx.x << 7;
  const int lr = lane >> 3, lc = lane & 7;

  f32x4 acc[4][4] = {};

  for (int kt = 0; kt < K; kt += 64) {
    #pragma unroll
    for (int it = 0; it < 4; ++it) {
      int r0 = (wave << 5) + (it << 3);
      int rr = r0 + lr;
      int gch = lc ^ (rr & 7);
      async_ld16(A + (size_t)(row0 + rr) * K + kt + (gch << 3), sA + (r0 << 6));
      async_ld16(W + (size_t)(col0 + rr) * K + kt + (gch << 3), sB + (r0 << 6));
    }
    __syncthreads();
    #pragma unroll
    for (int kk = 0; kk < 2; ++kk) {
      bf16x8 af[4];
      #pragma unroll
      for (int i = 0; i < 4; ++i) {
        int m = (wm << 6) + (i << 4) + l16;
        af[i] = *(const bf16x8*)&sA[(m << 6) + ((((kk << 2) + quad) ^ (l16 & 7)) << 3)];
      }
      #pragma unroll
      for (int j = 0; j < 4; ++j) {
        int n = (wn << 6) + (j << 4) + l16;
        bf16x8 bfr = *(const bf16x8*)&sB[(n << 6) + ((((kk << 2) + quad) ^ (l16 & 7)) << 3)];
        #pragma unroll
        for (int i = 0; i < 4; ++i)
          acc[i][j] = __builtin_amdgcn_mfma_f32_16x16x32_bf16(af[i], bfr, acc[i][j], 0, 0, 0);
      }
    }
    __syncthreads();
  }

  // epilogue: wave-private 64x36 f32 LDS tile, 2 passes of 32 cols
  float* ct = (float*)ldsraw + wave * (64 * 36);
  #pragma unroll
  for (int p = 0; p < 2; ++p) {
    #pragma unroll
    for (int i = 0; i < 4; ++i)
      #pragma unroll
      for (int r = 0; r < 4; ++r) {
        int row = (i << 4) + (quad << 2) + r;
        ct[row * 36 + l16]      = acc[i][(p << 1) + 0][r];
        ct[row * 36 + 16 + l16] = acc[i][(p << 1) + 1][r];
      }
    float4 sS = make_float4(0.f, 0.f, 0.f, 0.f);
    float4 sD = make_float4(0.f, 0.f, 0.f, 0.f);
    // same-wave LDS write->read ordering handled by compiler waitcnt
    #pragma unroll
    for (int it2 = 0; it2 < 8; ++it2) {
      int row = (it2 << 3) + lr;
      int c4 = lc << 2;
      float4 v = *(const float4*)&ct[row * 36 + c4];
      int gcol = col0 + (wn << 6) + (p << 5) + c4;
      size_t gidx = (size_t)(row0 + (wm << 6) + row) * Nn + gcol;
      if (FLAGS & GF_ALS) {
        float asv = b2f(asp[row0 + (wm << 6) + row]);
        float adv = b2f(adp[row0 + (wm << 6) + row]);
        sS.x += asv * v.x; sS.y += asv * v.y; sS.z += asv * v.z; sS.w += asv * v.w;
        sD.x += adv * v.x; sD.y += adv * v.y; sD.z += adv * v.z; sD.w += adv * v.w;
      }
      if (bias) {
        float4 bv = load4(bias + gcol);
        v.x += bv.x; v.y += bv.y; v.z += bv.z; v.w += bv.w;
      }
      if (FLAGS & GF_GELU) {
        v.x = gelu_f(v.x); v.y = gelu_f(v.y); v.z = gelu_f(v.z); v.w = gelu_f(v.w);
      }
      if (FLAGS & GF_RES) {
        float4 rv = *(const float4*)&res[gidx];
        v.x += rv.x; v.y += rv.y; v.z += rv.z; v.w += rv.w;
      }
      storev(C + gidx, v);
      if (FLAGS & GF_MIR) store4(C2 + gidx, v);
    }
    if (FLAGS & GF_ALS) {
      #pragma unroll
      for (int o = 8; o < 64; o <<= 1) {
        sS.x += __shfl_xor(sS.x, o); sS.y += __shfl_xor(sS.y, o);
        sS.z += __shfl_xor(sS.z, o); sS.w += __shfl_xor(sS.w, o);
        sD.x += __shfl_xor(sD.x, o); sD.y += __shfl_xor(sD.y, o);
        sD.z += __shfl_xor(sD.z, o); sD.w += __shfl_xor(sD.w, o);
      }
      if (lr == 0) {
        int node = col0 + (wn << 6) + (p << 5) + (lc << 2);
        int hd2 = blockIdx.y >> 1;
        int slice = ((blockIdx.y & 1) << 1) | wm;
        *(float4*)&alsp[(size_t)((slice << 3) + hd2) * Nn + node] = sS;
        *(float4*)&alsp[(size_t)((slice << 3) + 4 + hd2) * Nn + node] = sD;
      }
    }
  }
}

// ---------------------------------------------------------------------------
// gemm_rln: residual GEMM with fused epilogue.  C-tile = 32 rows x 256 cols
// (full row), grid = M/32 blocks (36 KB LDS -> 4 blocks/CU for latency hiding).
// h += A*W^T + bias (f32, in/out);
// POOL=false: tn = LN(h_new) (bf16)
// POOL=true:  hbm = bf16(h_new) mirror; logits[row] = dot(h_new_row, pw)+pbp[0]
// Nn fixed = 256, K%64==0.
// ---------------------------------------------------------------------------
template<bool POOL>
__global__ __launch_bounds__(256) void gemm_rln(
    const bf16* __restrict__ A, const bf16* __restrict__ W,
    const bf16* __restrict__ bias, float* __restrict__ h,
    bf16* __restrict__ tn, const bf16* __restrict__ lng,
    const bf16* __restrict__ lnb, int K,
    bf16* __restrict__ hbm, const bf16* __restrict__ pw,
    const bf16* __restrict__ pbp, float* __restrict__ logits)
{
  __shared__ __align__(16) char ldsraw[36864];   // staging 36 KB | epilogue 32.5 KB
  unsigned short* sA = (unsigned short*)ldsraw;  // 32 x 64 shorts
  unsigned short* sB = sA + 32 * 64;             // 256 x 64 shorts
  const int tid = threadIdx.x;
  const int wave = tid >> 6, lane = tid & 63;
  const int quad = lane >> 4, l16 = lane & 15;
  const int row0 = blockIdx.x << 5;
  const int lr = lane >> 3, lc = lane & 7;

  f32x4 acc[2][4] = {};

  for (int kt = 0; kt < K; kt += 64) {
    {
      int rr = (wave << 3) + lr;
      int gch = lc ^ (rr & 7);
      async_ld16(A + (size_t)(row0 + rr) * K + kt + (gch << 3), sA + (wave << 9));
    }
    #pragma unroll
    for (int it = 0; it < 8; ++it) {
      int r0 = (wave << 6) + (it << 3);
      int rr = r0 + lr;
      int gch = lc ^ (rr & 7);
      async_ld16(W + (size_t)rr * K + kt + (gch << 3), sB + (r0 << 6));
    }
    __syncthreads();
    #pragma unroll
    for (int kk = 0; kk < 2; ++kk) {
      bf16x8 af[2];
      #pragma unroll
      for (int i = 0; i < 2; ++i) {
        int m = (i << 4) + l16;
        af[i] = *(const bf16x8*)&sA[(m << 6) + ((((kk << 2) + quad) ^ (l16 & 7)) << 3)];
      }
      #pragma unroll
      for (int j = 0; j < 4; ++j) {
        int n = (wave << 6) + (j << 4) + l16;
        bf16x8 bfr = *(const bf16x8*)&sB[(n << 6) + ((((kk << 2) + quad) ^ (l16 & 7)) << 3)];
        #pragma unroll
        for (int i = 0; i < 2; ++i)
          acc[i][j] = __builtin_amdgcn_mfma_f32_16x16x32_bf16(af[i], bfr, acc[i][j], 0, 0, 0);
      }
    }
    __syncthreads();
  }

  // scatter acc into shared 32 x 260 f32 tile (full rows in one block)
  float* ct = (float*)ldsraw;
  #pragma unroll
  for (int j = 0; j < 4; ++j) {
    int col = (wave << 6) + (j << 4) + l16;
    #pragma unroll
    for (int i = 0; i < 2; ++i)
      #pragma unroll
      for (int r = 0; r < 4; ++r)
        ct[((i << 4) + (quad << 2) + r) * 260 + col] = acc[i][j][r];
  }
  __syncthreads();

  // thread = (row, eighth): 8 threads per row, 32 cols each, all in regs
  const int row = tid >> 3, q = tid & 7;
  const int c0 = q << 5;
  size_t gr = (size_t)(row0 + row) * 256 + c0;
  float4 v[8];
  float s1 = 0.f;
  #pragma unroll
  for (int k = 0; k < 8; ++k) {
    float4 cv = *(const float4*)&ct[row * 260 + c0 + (k << 2)];
    float4 bv = load4(bias + c0 + (k << 2));
    float4 rv = *(const float4*)&h[gr + (k << 2)];
    v[k].x = cv.x + bv.x + rv.x;
    v[k].y = cv.y + bv.y + rv.y;
    v[k].z = cv.z + bv.z + rv.z;
    v[k].w = cv.w + bv.w + rv.w;
    *(float4*)&h[gr + (k << 2)] = v[k];
    if (POOL) store4(hbm + gr + (k << 2), v[k]);
    s1 += v[k].x + v[k].y + v[k].z + v[k].w;
  }
  if (POOL) {
    float dp = 0.f;
    #pragma unroll
    for (int k = 0; k < 8; ++k) {
      float4 wv = load4(pw + c0 + (k << 2));
      dp += v[k].x * wv.x + v[k].y * wv.y + v[k].z * wv.z + v[k].w * wv.w;
    }
    dp += __shfl_xor(dp, 1); dp += __shfl_xor(dp, 2); dp += __shfl_xor(dp, 4);
    if (q == 0) logits[row0 + row] = dp + b2f(pbp[0]);
  } else {
    s1 += __shfl_xor(s1, 1); s1 += __shfl_xor(s1, 2); s1 += __shfl_xor(s1, 4);
    float mean = s1 * (1.0f / 256.0f);
    float s2 = 0.f;
    #pragma unroll
    for (int k = 0; k < 8; ++k) {
      float dx = v[k].x - mean, dy = v[k].y - mean, dz = v[k].z - mean, dw = v[k].w - mean;
      s2 += dx * dx + dy * dy + dz * dz + dw * dw;
    }
    s2 += __shfl_xor(s2, 1); s2 += __shfl_xor(s2, 2); s2 += __shfl_xor(s2, 4);
    float rstd = rsqrtf(s2 * (1.0f / 256.0f) + 1e-5f);
    #pragma unroll
    for (int k = 0; k < 8; ++k) {
      float4 gv = load4(lng + c0 + (k << 2));
      float4 bv2 = load4(lnb + c0 + (k << 2));
      float4 y;
      y.x = (v[k].x - mean) * rstd * gv.x + bv2.x;
      y.y = (v[k].y - mean) * rstd * gv.y + bv2.y;
      y.z = (v[k].z - mean) * rstd * gv.z + bv2.z;
      y.w = (v[k].w - mean) * rstd * gv.w + bv2.w;
      store4(tn + gr + (k << 2), y);
    }
  }
}

// ---------------------------------------------------------------------------
// gemm_pol: back-to-back policy head.  out = gelu(A@W1^T + b1) @ W2^T + b2.
// 32 rows/block; intermediate kept in LDS (bf16, XOR-swizzled for MFMA reads).
// ---------------------------------------------------------------------------
__global__ __launch_bounds__(256) void gemm_pol(
    const bf16* __restrict__ A, const bf16* __restrict__ W1,
    const bf16* __restrict__ b1, const bf16* __restrict__ W2,
    const bf16* __restrict__ b2p, bf16* __restrict__ out)
{
  __shared__ __align__(16) char ldsraw[36864];
  __shared__ __align__(16) unsigned short inter[4][2048];   // 4 kt-chunks x 32x64
  unsigned short* sA = (unsigned short*)ldsraw;
  unsigned short* sB = sA + 32 * 64;
  const int tid = threadIdx.x;
  const int wave = tid >> 6, lane = tid & 63;
  const int quad = lane >> 4, l16 = lane & 15;
  const int row0 = blockIdx.x << 5;
  const int lr = lane >> 3, lc = lane & 7;
  float* ct = (float*)ldsraw;
  const int row = tid >> 3, q = tid & 7;
  const int c0 = q << 5;

  // pass 1: T = gelu(A @ W1^T + b1)  -> inter (bf16, swizzled)
  {
    f32x4 acc[2][4] = {};
    for (int kt = 0; kt < 256; kt += 64) {
      { int rr = (wave << 3) + lr; int gch = lc ^ (rr & 7);
        async_ld16(A + (size_t)(row0 + rr) * 256 + kt + (gch << 3), sA + (wave << 9)); }
      #pragma unroll
      for (int it = 0; it < 8; ++it) {
        int r0 = (wave << 6) + (it << 3); int rr = r0 + lr; int gch = lc ^ (rr & 7);
        async_ld16(W1 + (size_t)rr * 256 + kt + (gch << 3), sB + (r0 << 6));
      }
      __syncthreads();
      #pragma unroll
      for (int kk = 0; kk < 2; ++kk) {
        bf16x8 af[2];
        #pragma unroll
        for (int i = 0; i < 2; ++i) {
          int m = (i << 4) + l16;
          af[i] = *(const bf16x8*)&sA[(m << 6) + ((((kk << 2) + quad) ^ (l16 & 7)) << 3)];
        }
        #pragma unroll
        for (int j = 0; j < 4; ++j) {
          int n = (wave << 6) + (j << 4) + l16;
          bf16x8 bfr = *(const bf16x8*)&sB[(n << 6) + ((((kk << 2) + quad) ^ (l16 & 7)) << 3)];
          #pragma unroll
          for (int i = 0; i < 2; ++i)
            acc[i][j] = __builtin_amdgcn_mfma_f32_16x16x32_bf16(af[i], bfr, acc[i][j], 0, 0, 0);
        }
      }
      __syncthreads();
    }
    #pragma unroll
    for (int j = 0; j < 4; ++j) {
      int col = (wave << 6) + (j << 4) + l16;
      #pragma unroll
      for (int i = 0; i < 2; ++i)
        #pragma unroll
        for (int r = 0; r < 4; ++r)
          ct[((i << 4) + (quad << 2) + r) * 260 + col] = acc[i][j][r];
    }
    __syncthreads();
    #pragma unroll
    for (int k = 0; k < 8; ++k) {
      int col = c0 + (k << 2);
      float4 cv = *(const float4*)&ct[row * 260 + col];
      float4 bv = load4(b1 + col);
      unsigned short u[4] = { f2us(gelu_f(cv.x + bv.x)), f2us(gelu_f(cv.y + bv.y)),
                              f2us(gelu_f(cv.z + bv.z)), f2us(gelu_f(cv.w + bv.w)) };
      int ktb = col >> 6, cc = col & 63, ch = cc >> 3, wc = cc & 7;
      *(ushort4*)&inter[ktb][(row << 6) + ((ch ^ (row & 7)) << 3) + wc] = *(ushort4*)u;
    }
  }
  __syncthreads();

  // pass 2: out = T @ W2^T + b2
  {
    f32x4 acc[2][4] = {};
    #pragma unroll
    for (int kt2 = 0; kt2 < 4; ++kt2) {
      #pragma unroll
      for (int it = 0; it < 8; ++it) {
        int r0 = (wave << 6) + (it << 3); int rr = r0 + lr; int gch = lc ^ (rr & 7);
        async_ld16(W2 + (size_t)rr * 256 + (kt2 << 6) + (gch << 3), sB + (r0 << 6));
      }
      __syncthreads();
      #pragma unroll
      for (int kk = 0; kk < 2; ++kk) {
        bf16x8 af[2];
        #pragma unroll
        for (int i = 0; i < 2; ++i) {
          int m = (i << 4) + l16;
          af[i] = *(const bf16x8*)&inter[kt2][(m << 6) + ((((kk << 2) + quad) ^ (l16 & 7)) << 3)];
        }
        #pragma unroll
        for (int j = 0; j < 4; ++j) {
          int n = (wave << 6) + (j << 4) + l16;
          bf16x8 bfr = *(const bf16x8*)&sB[(n << 6) + ((((kk << 2) + quad) ^ (l16 & 7)) << 3)];
          #pragma unroll
          for (int i = 0; i < 2; ++i)
            acc[i][j] = __builtin_amdgcn_mfma_f32_16x16x32_bf16(af[i], bfr, acc[i][j], 0, 0, 0);
        }
      }
      __syncthreads();
    }
    #pragma unroll
    for (int j = 0; j < 4; ++j) {
      int col = (wave << 6) + (j << 4) + l16;
      #pragma unroll
      for (int i = 0; i < 2; ++i)
        #pragma unroll
        for (int r = 0; r < 4; ++r)
          ct[((i << 4) + (quad << 2) + r) * 260 + col] = acc[i][j][r];
    }
    __syncthreads();
    #pragma unroll
    for (int k = 0; k < 8; ++k) {
      int col = c0 + (k << 2);
      float4 cv = *(const float4*)&ct[row * 260 + col];
      float4 bv = load4(b2p + col);
      store4(out + (size_t)(row0 + row) * 256 + col,
             make_float4(cv.x + bv.x, cv.y + bv.y, cv.z + bv.z, cv.w + bv.w));
    }
  }
}

// ---------------------------------------------------------------------------
// heads_fused: value + uncertainty heads in one kernel (32 graphs/block).
// value = tanh(gelu(g_rep@vw1^T+vb1) @ vw2 + vb2)
// unc   = softplus(gelu(g_rep@uw1^T+ub1) @ uw2 + ub2)
// ---------------------------------------------------------------------------
__global__ __launch_bounds__(256) void heads_fused(
    const bf16* __restrict__ g_rep,
    const bf16* __restrict__ vw1, const bf16* __restrict__ vb1,
    const bf16* __restrict__ vw2, const bf16* __restrict__ vb2,
    const bf16* __restrict__ uw1, const bf16* __restrict__ ub1,
    const bf16* __restrict__ uw2, const bf16* __restrict__ ub2,
    bf16* __restrict__ o_val, bf16* __restrict__ o_unc)
{
  __shared__ __align__(16) char ldsraw[36864];
  unsigned short* sA = (unsigned short*)ldsraw;
  unsigned short* sB = sA + 32 * 64;
  const int tid = threadIdx.x;
  const int wave = tid >> 6, lane = tid & 63;
  const int quad = lane >> 4, l16 = lane & 15;
  const int row0 = blockIdx.x << 5;
  const int lr = lane >> 3, lc = lane & 7;
  float* ct = (float*)ldsraw;
  const int row = tid >> 3, q = tid & 7;
  const int c0 = q << 5;

  // ---- value head (Nn=256) ----
  {
    f32x4 acc[2][4] = {};
    for (int kt = 0; kt < 256; kt += 64) {
      { int rr = (wave << 3) + lr; int gch = lc ^ (rr & 7);
        async_ld16(g_rep + (size_t)(row0 + rr) * 256 + kt + (gch << 3), sA + (wave << 9)); }
      #pragma unroll
      for (int it = 0; it < 8; ++it) {
        int r0 = (wave << 6) + (it << 3); int rr = r0 + lr; int gch = lc ^ (rr & 7);
        async_ld16(vw1 + (size_t)rr * 256 + kt + (gch << 3), sB + (r0 << 6));
      }
      __syncthreads();
      #pragma unroll
      for (int kk = 0; kk < 2; ++kk) {
        bf16x8 af[2];
        #pragma unroll
        for (int i = 0; i < 2; ++i) {
          int m = (i << 4) + l16;
          af[i] = *(const bf16x8*)&sA[(m << 6) + ((((kk << 2) + quad) ^ (l16 & 7)) << 3)];
        }
        #pragma unroll
        for (int j = 0; j < 4; ++j) {
          int n = (wave << 6) + (j << 4) + l16;
          bf16x8 bfr = *(const bf16x8*)&sB[(n << 6) + ((((kk << 2) + quad) ^ (l16 & 7)) << 3)];
          #pragma unroll
          for (int i = 0; i < 2; ++i)
            acc[i][j] = __builtin_amdgcn_mfma_f32_16x16x32_bf16(af[i], bfr, acc[i][j], 0, 0, 0);
        }
      }
      __syncthreads();
    }
    #pragma unroll
    for (int j = 0; j < 4; ++j) {
      int col = (wave << 6) + (j << 4) + l16;
      #pragma unroll
      for (int i = 0; i < 2; ++i)
        #pragma unroll
        for (int r = 0; r < 4; ++r)
          ct[((i << 4) + (quad << 2) + r) * 260 + col] = acc[i][j][r];
    }
    __syncthreads();
    float dp = 0.f;
    #pragma unroll
    for (int k = 0; k < 8; ++k) {
      float4 cv = *(const float4*)&ct[row * 260 + c0 + (k << 2)];
      float4 bv = load4(vb1 + c0 + (k << 2));
      float4 wv = load4(vw2 + c0 + (k << 2));
      dp += gelu_f(cv.x + bv.x) * wv.x + gelu_f(cv.y + bv.y) * wv.y
          + gelu_f(cv.z + bv.z) * wv.z + gelu_f(cv.w + bv.w) * wv.w;
    }
    dp += __shfl_xor(dp, 1); dp += __shfl_xor(dp, 2); dp += __shfl_xor(dp, 4);
    if (q == 0) o_val[row0 + row] = f2b(tanhf(dp + b2f(vb2[0])));
  }
  __syncthreads();

  // ---- uncertainty head (Nn=128; waves 0-1 own cols, others duplicate) ----
  {
    f32x4 acc[2][4] = {};
    for (int kt = 0; kt < 256; kt += 64) {
      { int rr = (wave << 3) + lr; int gch = lc ^ (rr & 7);
        async_ld16(g_rep + (size_t)(row0 + rr) * 256 + kt + (gch << 3), sA + (wave << 9)); }
      #pragma unroll
      for (int it = 0; it < 4; ++it) {
        int r0 = (wave << 5) + (it << 3); int rr = r0 + lr; int gch = lc ^ (rr & 7);
        async_ld16(uw1 + (size_t)rr * 256 + kt + (gch << 3), sB + (r0 << 6));
      }
      __syncthreads();
      #pragma unroll
      for (int kk = 0; kk < 2; ++kk) {
        bf16x8 af[2];
        #pragma unroll
        for (int i = 0; i < 2; ++i) {
          int m = (i << 4) + l16;
          af[i] = *(const bf16x8*)&sA[(m << 6) + ((((kk << 2) + quad) ^ (l16 & 7)) << 3)];
        }
        #pragma unroll
        for (int j = 0; j < 4; ++j) {
          int n = ((wave & 1) << 6) + (j << 4) + l16;
          bf16x8 bfr = *(const bf16x8*)&sB[(n << 6) + ((((kk << 2) + quad) ^ (l16 & 7)) << 3)];
          #pragma unroll
          for (int i = 0; i < 2; ++i)
            acc[i][j] = __builtin_amdgcn_mfma_f32_16x16x32_bf16(af[i], bfr, acc[i][j], 0, 0, 0);
        }
      }
      __syncthreads();
    }
    if (wave < 2) {
      #pragma unroll
      for (int j = 0; j < 4; ++j) {
        int col = (wave << 6) + (j << 4) + l16;
        #pragma unroll
        for (int i = 0; i < 2; ++i)
          #pragma unroll
          for (int r = 0; r < 4; ++r)
            ct[((i << 4) + (quad << 2) + r) * 260 + col] = acc[i][j][r];
      }
    }
    __syncthreads();
    float dp = 0.f;
    if (q < 4) {
      #pragma unroll
      for (int k = 0; k < 8; ++k) {
        float4 cv = *(const float4*)&ct[row * 260 + c0 + (k << 2)];
        float4 bv = load4(ub1 + c0 + (k << 2));
        float4 wv = load4(uw2 + c0 + (k << 2));
        dp += gelu_f(cv.x + bv.x) * wv.x + gelu_f(cv.y + bv.y) * wv.y
            + gelu_f(cv.z + bv.z) * wv.z + gelu_f(cv.w + bv.w) * wv.w;
      }
    }
    dp += __shfl_xor(dp, 1); dp += __shfl_xor(dp, 2); dp += __shfl_xor(dp, 4);
    if (q == 0) {
      float x = dp + b2f(ub2[0]);
      float sp = (x > 20.f) ? x : log1pf(expf(x));
      o_unc[row0 + row] = f2b(sp);
    }
  }
}

// ---------------------------------------------------------------------------
// CSR build over dst
// ---------------------------------------------------------------------------
__global__ void csr_count(const int* __restrict__ edst, int* __restrict__ cnt){
  int e = blockIdx.x * 256 + threadIdx.x;
  if (e < NE2) {
    int d = (e < NE) ? edst[e] : (e - NE);
    atomicAdd(&cnt[d], 1);
  }
}
__global__ __launch_bounds__(1024) void csr_scan(const int* __restrict__ cnt, int* __restrict__ off){
  __shared__ int ls[1024];
  int t = threadIdx.x;
  int base = t * 16;
  int loc[16]; int s = 0;
  #pragma unroll
  for (int j = 0; j < 16; ++j) { loc[j] = s; s += cnt[base + j]; }
  ls[t] = s;
  __syncthreads();
  for (int o = 1; o < 1024; o <<= 1) {
    int v = (t >= o) ? ls[t - o] : 0;
    __syncthreads();
    ls[t] += v;
    __syncthreads();
  }
  int pre = (t == 0) ? 0 : ls[t - 1];
  #pragma unroll
  for (int j = 0; j < 16; ++j) off[base + j] = pre + loc[j];
  if (t == 1023) off[N_NODES] = ls[1023];
}
__global__ void csr_fill(const int* __restrict__ edst, const int* __restrict__ off,
                         int* __restrict__ fillc, int* __restrict__ list){
  int e = blockIdx.x * 256 + threadIdx.x;
  if (e < NE2) {
    int d = (e < NE) ? edst[e] : (e - NE);
    int p = atomicAdd(&fillc[d], 1);
    list[off[d] + p] = e;
  }
}

// ---------------------------------------------------------------------------
// GAT per-(graph,head) block (async-staged hpT, precomputed als/ald).
// NOTE (R9): B-fragment is a transpose read (lane = channel row) — direct
// global reads are lane-per-row gathers (64 cache lines/instr) and cost
// +17 µs/layer.  LDS staging via pre-swizzled async_ld16 is required.
// ---------------------------------------------------------------------------
#define ALF_S 68

__device__ __forceinline__ bf16x8 pack8(const float* v, float scale){
  unsigned short u[8];
  #pragma unroll
  for (int t = 0; t < 8; ++t) u[t] = f2us(v[t] * scale);
  bf16x8 r; __builtin_memcpy(&r, u, 16); return r;
}

__global__ __launch_bounds__(256) void gat_graph2(
    const int* __restrict__ esrc, const bf16* __restrict__ hpT_g,
    const int* __restrict__ off, const int* __restrict__ list,
    const float* __restrict__ alsp,
    bf16* __restrict__ msg4, int g0, int hn)
{
  __shared__ unsigned short hpT[256 * 64];
  __shared__ float alpha[64 * ALF_S];
  __shared__ float als[64], ald[64], dinv[64];

  const int hd = blockIdx.x & 3;
  const int lg = blockIdx.x >> 2;
  const int g  = g0 + lg;
  const int tid = threadIdx.x;
  const int wave = tid >> 6, lane = tid & 63;
  const int quad = lane >> 4, l16 = lane & 15;
  const int nd = tid >> 2;
  const int k4 = tid & 3;

  {
    const int rl = lane >> 3, jj = lane & 7;
    #pragma unroll
    for (int it = 0; it < 8; ++it) {
      int c = (it << 5) + (wave << 3) + rl;
      async_ld16(hpT_g + (size_t)((hd << 8) + c) * 16384 + (g << 6) + ((jj ^ (c & 7)) << 3),
                 hpT + (((it << 5) + (wave << 3)) << 6));
    }
  }
  if (tid < 128) {
    int n2 = tid & 63;
    int sd = (tid >> 6) << 2;                 // 0 = als, 4 = ald
    float v = 0.f;
    #pragma unroll
    for (int sl = 0; sl < 4; ++sl)
      v += alsp[(size_t)((sl << 3) + sd + hd) * 16384 + (g << 6) + n2];
    if (sd) ald[n2] = v; else als[n2] = v;
  }
  #pragma unroll
  for (int idx = tid; idx < 64 * ALF_S; idx += 256) alpha[idx] = 0.f;
  __syncthreads();

  {
    int st = off[(g << 6) + nd];
    int deg = off[(g << 6) + nd + 1] - st;
    float ad = ald[nd];
    float mx = -1e30f;
    for (int e = k4; e < deg; e += 4) {
      int ed = list[st + e];
      int sl = ((ed < NE) ? esrc[ed] : (ed - NE)) - (g << 6);
      float v = als[sl] + ad;
      v = (v > 0.f) ? v : 0.2f * v;
      mx = fmaxf(mx, v);
    }
    mx = fmaxf(mx, __shfl_xor(mx, 1)); mx = fmaxf(mx, __shfl_xor(mx, 2));
    float den = 0.f;
    for (int e = k4; e < deg; e += 4) {
      int ed = list[st + e];
      int sl = ((ed < NE) ? esrc[ed] : (ed - NE)) - (g << 6);
      float v = als[sl] + ad;
      v = (v > 0.f) ? v : 0.2f * v;
      float w = __expf(v - mx);
      den += w;
      atomicAdd(&alpha[nd * ALF_S + sl], w);
    }
    den += __shfl_xor(den, 1); den += __shfl_xor(den, 2);
    if (k4 == 0) dinv[nd] = 1.0f / den;
  }
  __syncthreads();

  f32x4 acc[4][4] = {};
  #pragma unroll
  for (int kk = 0; kk < 2; ++kk) {
    bf16x8 af[4];
    #pragma unroll
    for (int i = 0; i < 4; ++i) {
      int m = (i << 4) + l16;
      const float* ap = &alpha[m * ALF_S + (kk << 5) + (quad << 3)];
      float av[8];
      float4 a0 = *(const float4*)ap, a1 = *(const float4*)(ap + 4);
      av[0]=a0.x; av[1]=a0.y; av[2]=a0.z; av[3]=a0.w;
      av[4]=a1.x; av[5]=a1.y; av[6]=a1.z; av[7]=a1.w;
      af[i] = pack8(av, dinv[m]);
    }
    #pragma unroll
    for (int j = 0; j < 4; ++j) {
      int c2 = (wave << 6) + (j << 4) + l16;
      int chunk = (kk << 2) + quad;
      bf16x8 bfr = *(const bf16x8*)&hpT[(c2 << 6) + ((chunk ^ (c2 & 7)) << 3)];
      #pragma unroll
      for (int i = 0; i < 4; ++i)
        acc[i][j] = __builtin_amdgcn_mfma_f32_16x16x32_bf16(af[i], bfr, acc[i][j], 0, 0, 0);
    }
  }

  #pragma unroll
  for (int j = 0; j < 4; ++j) {
    int col = (wave << 6) + (j << 4) + l16;
    #pragma unroll
    for (int i = 0; i < 4; ++i) {
      int rbase = (i << 4) + (quad << 2);
      #pragma unroll
      for (int r = 0; r < 4; ++r)
        msg4[((size_t)hd * hn + (lg << 6) + rbase + r) * 256 + col] = f2b(acc[i][j][r]);
    }
  }
}

// Head-mean + bias + LayerNorm + GELU + residual; writes f32 h + bf16 mirror hb.
// Optional second LN (lng/lnb/tno): tn = LN(h_new) for the following TF layer.
__global__ __launch_bounds__(256) void gat_epi(
    const bf16* __restrict__ msg4, int hn, int n0,
    const bf16* __restrict__ bias, const bf16* __restrict__ gg, const bf16* __restrict__ gb,
    float* __restrict__ h, bf16* __restrict__ hb,
    const bf16* __restrict__ lng, const bf16* __restrict__ lnb, bf16* __restrict__ tno)
{
  int nl = blockIdx.x * 4 + (threadIdx.x >> 6);
  int lane = threadIdx.x & 63;
  int c = lane * 4;
  float4 s = make_float4(0.f, 0.f, 0.f, 0.f);
  #pragma unroll
  for (int hd = 0; hd < 4; ++hd) {
    float4 m = load4(msg4 + ((size_t)hd * hn + nl) * 256 + c);
    s.x += m.x; s.y += m.y; s.z += m.z; s.w += m.w;
  }
  float4 bv = load4(bias + c);
  float ox = s.x * 0.25f + bv.x, oy = s.y * 0.25f + bv.y;
  float oz = s.z * 0.25f + bv.z, ow = s.w * 0.25f + bv.w;
  float mean = wave_sum(ox + oy + oz + ow) * (1.0f / 256.0f);
  float dx = ox - mean, dy = oy - mean, dz = oz - mean, dw = ow - mean;
  float var = wave_sum(dx*dx + dy*dy + dz*dz + dw*dw) * (1.0f / 256.0f);
  float r = rsqrtf(var + 1e-5f);
  float4 gv = load4(gg + c); float4 b2 = load4(gb + c);
  size_t base = ((size_t)(n0 + nl)) * 256 + c;
  float4 hv = load4(h + base);
  hv.x += gelu_f(dx * r * gv.x + b2.x);
  hv.y += gelu_f(dy * r * gv.y + b2.y);
  hv.z += gelu_f(dz * r * gv.z + b2.z);
  hv.w += gelu_f(dw * r * gv.w + b2.w);
  store4(h + base, hv);
  store4(hb + base, hv);
  if (lng) {
    float m2 = wave_sum(hv.x + hv.y + hv.z + hv.w) * (1.0f / 256.0f);
    float ex = hv.x - m2, ey = hv.y - m2, ez = hv.z - m2, ew = hv.w - m2;
    float v2 = wave_sum(ex*ex + ey*ey + ez*ez + ew*ew) * (1.0f / 256.0f);
    float r2 = rsqrtf(v2 + 1e-5f);
    float4 g2 = load4(lng + c); float4 bb = load4(lnb + c);
    store4(tno + base, make_float4(ex*r2*g2.x + bb.x, ey*r2*g2.y + bb.y,
                                   ez*r2*g2.z + bb.z, ew*r2*g2.w + bb.w));
  }
}

// ---------------------------------------------------------------------------
// LayerNorm: wave-per-row (4 rows/block), f32 in, bf16 out (fallback path)
// ---------------------------------------------------------------------------
__global__ __launch_bounds__(256) void ln_kernel(
    const float* __restrict__ x, bf16* __restrict__ y,
    const bf16* __restrict__ g, const bf16* __restrict__ b)
{
  int row = blockIdx.x * 4 + (threadIdx.x >> 6);
  int lane = threadIdx.x & 63;
  int c = lane * 4;
  float4 v = load4(x + (size_t)row * 256 + c);
  float mean = wave_sum(v.x + v.y + v.z + v.w) * (1.0f / 256.0f);
  float dx = v.x - mean, dy = v.y - mean, dz = v.z - mean, dw = v.w - mean;
  float var = wave_sum(dx*dx + dy*dy + dz*dz + dw*dw) * (1.0f / 256.0f);
  float r = rsqrtf(var + 1e-5f);
  float4 gv = load4(g + c); float4 bv = load4(b + c);
  store4(y + (size_t)row * 256 + c,
         make_float4(dx*r*gv.x + bv.x, dy*r*gv.y + bv.y, dz*r*gv.z + bv.z, dw*r*gv.w + bv.w));
}

// ---------------------------------------------------------------------------
// MFMA flash-style attention (unchanged)
// ---------------------------------------------------------------------------
#define VT_LDS 268
#define P_LDS  72

__global__ __launch_bounds__(256) void attn_mfma(
    const bf16* __restrict__ qkv, bf16* __restrict__ obuf)
{
  const int b  = blockIdx.x & 63;
  const int hh = blockIdx.x >> 6;
  __shared__ unsigned short VTs[32 * VT_LDS];
  __shared__ unsigned short Ps[4][64 * P_LDS];
  const int tid  = threadIdx.x;
  const int wave = tid >> 6, lane = tid & 63;
  const int quad = lane >> 4, l16 = lane & 15;

  {
    const bf16* vb = qkv + (size_t)(tid * 64 + b) * 768 + 512 + hh * 32;
    unsigned short vv[32];
    *(uint4*)&vv[0]  = *(const uint4*)(vb);
    *(uint4*)&vv[8]  = *(const uint4*)(vb + 8);
    *(uint4*)&vv[16] = *(const uint4*)(vb + 16);
    *(uint4*)&vv[24] = *(const uint4*)(vb + 24);
    #pragma unroll
    for (int d = 0; d < 32; ++d) VTs[d * VT_LDS + tid] = vv[d];
  }
  bf16x8 qf[4];
  #pragma unroll
  for (int i = 0; i < 4; ++i) {
    int s = (wave << 6) + (i << 4) + l16;
    qf[i] = *(const bf16x8*)(qkv + (size_t)(s * 64 + b) * 768 + hh * 32 + (quad << 3));
  }
  __syncthreads();

  const float scale = 0.17677669529663687f;
  f32x4 oacc[4][2] = {};
  float lsum[4][4] = {};
  unsigned short* Pw = &Ps[wave][0];

  for (int nt = 0; nt < 4; ++nt) {
    bf16x8 kf[4];
    #pragma unroll
    for (int j = 0; j < 4; ++j) {
      int t = (nt << 6) + (j << 4) + l16;
      kf[j] = *(const bf16x8*)(qkv + (size_t)(t * 64 + b) * 768 + 256 + hh * 32 + (quad << 3));
    }
    f32x4 zero = {0.f, 0.f, 0.f, 0.f};
    f32x4 sx[4][4];
    #pragma unroll
    for (int i = 0; i < 4; ++i)
      #pragma unroll
      for (int j = 0; j < 4; ++j)
        sx[i][j] = __builtin_amdgcn_mfma_f32_16x16x32_bf16(qf[i], kf[j], zero, 0, 0, 0);
    #pragma unroll
    for (int i = 0; i < 4; ++i) {
      #pragma unroll
      for (int r = 0; r < 4; ++r) {
        float p[4]; float rs = 0.f;
        #pragma unroll
        for (int j = 0; j < 4; ++j) {
          float sc = fminf(fmaxf(sx[i][j][r] * scale, -60.f), 60.f);
          p[j] = __expf(sc);
          rs += p[j];
        }
        #pragma unroll
        for (int o = 1; o < 16; o <<= 1) rs += __shfl_xor(rs, o);
        lsum[i][r] += rs;
        int row = (i << 4) + (quad << 2) + r;
        #pragma unroll
        for (int j = 0; j < 4; ++j)
          Pw[row * P_LDS + (j << 4) + l16] = f2us(p[j]);
      }
    }
    #pragma unroll
    for (int kk = 0; kk < 2; ++kk) {
      bf16x8 vf[2];
      #pragma unroll
      for (int j2 = 0; j2 < 2; ++j2)
        vf[j2] = *(const bf16x8*)&VTs[((j2 << 4) + l16) * VT_LDS + (nt << 6) + (kk << 5) + (quad << 3)];
      #pragma unroll
      for (int i2 = 0; i2 < 4; ++i2) {
        bf16x8 pf = *(const bf16x8*)&Pw[((i2 << 4) + l16) * P_LDS + (kk << 5) + (quad << 3)];
        #pragma unroll
        for (int j2 = 0; j2 < 2; ++j2)
          oacc[i2][j2] = __builtin_amdgcn_mfma_f32_16x16x32_bf16(pf, vf[j2], oacc[i2][j2], 0, 0, 0);
      }
    }
  }
  #pragma unroll
  for (int i = 0; i < 4; ++i) {
    #pragma unroll
    for (int r = 0; r < 4; ++r) {
      int srow = (wave << 6) + (i << 4) + (quad << 2) + r;
      float inv = 1.0f / lsum[i][r];
      #pragma unroll
      for (int j2 = 0; j2 < 2; ++j2)
        obuf[(size_t)(srow * 64 + b) * 256 + hh * 32 + (j2 << 4) + l16] = f2b(oacc[i][j2][r] * inv);
    }
  }
}

// ---------------------------------------------------------------------------
// Pooling (g_rep emitted bf16)
// ---------------------------------------------------------------------------
__global__ __launch_bounds__(1024) void pool_reduce(
    const float* __restrict__ logits, float* __restrict__ red)
{
  __shared__ float sm[16];
  int t = threadIdx.x;
  float m = -1e30f;
  for (int i = t; i < N_NODES; i += 1024) m = fmaxf(m, logits[i]);
  m = wave_max(m);
  if ((t & 63) == 0) sm[t >> 6] = m;
  __syncthreads();
  if (t == 0) { float mm = sm[0]; for (int i = 1; i < 16; ++i) mm = fmaxf(mm, sm[i]); sm[0] = mm; }
  __syncthreads();
  float gmax = sm[0];
  __syncthreads();
  float s = 0.f;
  for (int i = t; i < N_NODES; i += 1024) s += expf(logits[i] - gmax);
  s = wave_sum(s);
  if ((t & 63) == 0) sm[t >> 6] = s;
  __syncthreads();
  if (t == 0) { float ss = 0.f; for (int i = 0; i < 16; ++i) ss += sm[i]; red[0] = gmax; red[1] = 1.0f / ss; }
}
__global__ __launch_bounds__(256) void pool_grep(
    const float* __restrict__ h, const float* __restrict__ logits,
    const float* __restrict__ red, bf16* __restrict__ g_rep)
{
  __shared__ float w[64];
  int g = blockIdx.x; int tid = threadIdx.x;
  if (tid < 64) w[tid] = expf(logits[g * 64 + tid] - red[0]) * red[1];
  __syncthreads();
  float acc = 0.f;
  for (int nd = 0; nd < 64; ++nd) acc += h[((size_t)g * 64 + nd) * 256 + tid] * w[nd];
  g_rep[(size_t)g * 256 + tid] = f2b(acc);
}

// ---------------------------------------------------------------------------
extern "C" void kernel_launch(void* const* d_in, const int* in_sizes, int n_in,
                              void* d_out, int out_size, void* d_ws, size_t ws_size,
                              hipStream_t stream)
{
  (void)out_size;
  const int* eidx = (const int*)d_in[1];

  char* ws = (char*)d_ws;
  size_t wo = 0;
  auto alloc = [&](size_t bytes) -> char* {
    char* p = ws + wo; wo += (bytes + 255) & ~(size_t)255; return p;
  };
  int*   flags = (int*)alloc(256);
  int*   cnt   = (int*)alloc((size_t)N_NODES * 4);
  int*   fillc = (int*)alloc((size_t)N_NODES * 4);
  size_t zero_end = wo;

  bf16* conv[38] = {};
  static const int fidx[35] = {0,4,5,6,7,8,9,10,11,12,13,14,15,16,17,18,19,
                               20,21,22,23,24,25,26,27,28,29,30,31,32,33,34,35,36,37};
  for (int j = 0; j < 35; ++j) {
    int idx = fidx[j];
    conv[idx] = (bf16*)alloc((size_t)in_sizes[idx] * 2);
  }
  float* h     = (float*)alloc((size_t)N_NODES * 256 * 4);
  bf16*  hb    = (bf16*) alloc((size_t)N_NODES * 256 * 2);   // bf16 mirror of h
  bf16*  big   = (bf16*) alloc((size_t)N_NODES * 1024 * 2);
  const int OUT_ELEMS = 256 + N_NODES * 256 + 256;
  bf16*  tn     = (bf16*)alloc((size_t)N_NODES * 256 * 2);   // adjacent to ostage
  bf16*  ostage = (bf16*)alloc((size_t)OUT_ELEMS * 2);
  int*   off   = (int*)alloc((size_t)(N_NODES + 1) * 4);
  int*   list  = (int*)alloc((size_t)NE2 * 4);
  float* logits= (float*)alloc((size_t)N_NODES * 4);
  float* redb  = (float*)alloc(256);
  bf16*  g_rep = (bf16*)alloc((size_t)256 * 256 * 2);
  float* alsp  = (float*)alloc((size_t)32 * N_NODES * 4);    // 4 slices x (s,d) x 4 heads
  size_t base_needed = wo;

  if (n_in != 38)                   { write_sentinel<<<1,256,0,stream>>>((bf16*)d_out, 4.f);  return; }
  if (in_sizes[0] != N_NODES * 128) { write_sentinel<<<1,256,0,stream>>>((bf16*)d_out, 8.f);  return; }
  if (in_sizes[1] != 2 * NE)        { write_sentinel<<<1,256,0,stream>>>((bf16*)d_out, 16.f); return; }
  if (ws_size < base_needed)        { write_sentinel<<<1,256,0,stream>>>((bf16*)d_out, 32.f); return; }

  size_t msg_bytes = (size_t)4 * N_NODES * 256 * 2;
  bf16* msg4; int halves;
  if (ws_size >= base_needed + msg_bytes + 256) {
    msg4 = (bf16*)alloc(msg_bytes); halves = 1;
  } else {
    msg4 = tn; halves = 2;
  }

  hipMemsetAsync(d_ws, 0, zero_end, stream);

  detect_dtype<<<256, 256, 0, stream>>>((const unsigned short*)d_in[0], 65536, flags);
  {
    ConvArgs ca;
    int cum = 0;
    for (int j = 0; j < 35; ++j) {
      int idx = fidx[j];
      ca.src[j] = d_in[idx];
      ca.dst[j] = (unsigned short*)conv[idx];
      ca.cumg[j] = cum;
      ca.n[j] = in_sizes[idx];
      cum += (in_sizes[idx] + 3) >> 2;
    }
    ca.cumg[35] = cum;
    conv_all4<<<(cum + 255) / 256, 256, 0, stream>>>(ca, flags);
  }
  const bf16 *xb = conv[0], *emb_w = conv[4], *emb_b = conv[5], *gat_w = conv[6],
             *gat_as = conv[7], *gat_ad = conv[8], *gat_b = conv[9], *gnn_g = conv[10],
             *gnn_beta = conv[11], *ln1_g = conv[12], *ln1_b = conv[13], *in_w = conv[14],
             *in_b = conv[15], *out_w = conv[16], *out_b = conv[17], *ln2_g = conv[18],
             *ln2_b = conv[19], *ff1_w = conv[20], *ff1_b = conv[21], *ff2_w = conv[22],
             *ff2_b = conv[23], *pool_w = conv[24], *pool_b = conv[25],
             *vw1 = conv[26], *vb1 = conv[27], *vw2 = conv[28], *vb2 = conv[29],
             *pw1 = conv[30], *pb1 = conv[31], *pw2 = conv[32], *pb2 = conv[33],
             *uw1 = conv[34], *ub1 = conv[35], *uw2 = conv[36], *ub2 = conv[37];

  bf16* qkv  = big;
  bf16* obuf = big + (size_t)N_NODES * 768;
  bf16* hpT_g = big;          // [1024 ch][16384 nodes] transposed GAT projection
  bf16* ffb  = big;
  bf16* o_val = ostage;
  bf16* o_pol = ostage + 256;
  bf16* o_unc = ostage + 256 + (size_t)N_NODES * 256;

  csr_count<<<(NE2 + 255) / 256, 256, 0, stream>>>(eidx + NE, cnt);
  csr_scan<<<1, 1024, 0, stream>>>(cnt, off);
  csr_fill<<<(NE2 + 255) / 256, 256, 0, stream>>>(eidx + NE, off, fillc, list);

  // Embedding: h (f32) + hb (bf16 mirror)
  gemm2<float, GF_MIR><<<dim3(2, 128), 256, 0, stream>>>(
      xb, emb_w, emb_b, nullptr, h, hb, N_NODES, 256, 128,
      nullptr, nullptr, nullptr);

  const int gph = 256 / halves;
  const int hn  = N_NODES / halves;
  for (int l = 0; l < 8; ++l) {
    // transposed projection: hpT = gat_w[l] @ hb^T, [1024][16384];
    // epilogue also emits als/ald partial slices into alsp.
    gemm2<bf16, GF_ALS><<<dim3(128, 8), 256, 0, stream>>>(
        gat_w + (size_t)l * 1024 * 256, hb, nullptr, nullptr, hpT_g, nullptr,
        1024, N_NODES, 256, gat_as + l * 1024, gat_ad + l * 1024, alsp);
    const bf16* lng = (l == 7 && halves == 1) ? ln1_g : nullptr;
    const bf16* lnb = (l == 7 && halves == 1) ? ln1_b : nullptr;
    for (int ph = 0; ph < halves; ++ph) {
      gat_graph2<<<gph * 4, 256, 0, stream>>>(eidx, hpT_g, off, list, alsp,
          msg4, ph * gph, hn);
      gat_epi<<<hn / 4, 256, 0, stream>>>(msg4, hn, ph * hn,
          gat_b + l * 256, gnn_g + l * 256, gnn_beta + l * 256, h, hb,
          lng, lnb, tn);
    }
  }
  if (halves == 2)
    ln_kernel<<<N_NODES / 4, 256, 0, stream>>>(h, tn, ln1_g, ln1_b);

  for (int l = 0; l < 6; ++l) {
    // tn already holds LN1(h) (from gat_epi l=7 or previous layer's fused ff2)
    gemm2<bf16, 0><<<dim3(6, 128), 256, 0, stream>>>(
        tn, in_w + (size_t)l * 768 * 256, in_b + l * 768, nullptr, qkv, nullptr, N_NODES, 768, 256,
        nullptr, nullptr, nullptr);
    attn_mfma<<<512, 256, 0, stream>>>(qkv, obuf);
    // h += attnout @ out_w^T + out_b ; tn = LN2(h)
    gemm_rln<false><<<N_NODES / 32, 256, 0, stream>>>(
        obuf, out_w + (size_t)l * 256 * 256, out_b + l * 256, h, tn,
        ln2_g + l * 256, ln2_b + l * 256, 256,
        nullptr, nullptr, nullptr, nullptr);
    gemm2<bf16, GF_GELU><<<dim3(8, 128), 256, 0, stream>>>(
        tn, ff1_w + (size_t)l * 1024 * 256, ff1_b + l * 1024, nullptr, ffb, nullptr, N_NODES, 1024, 256,
        nullptr, nullptr, nullptr);
    if (l < 5)
      // h += ffb @ ff2_w^T + ff2_b ; tn = LN1[l+1](h)
      gemm_rln<false><<<N_NODES / 32, 256, 0, stream>>>(
          ffb, ff2_w + (size_t)l * 256 * 1024, ff2_b + l * 256, h, tn,
          ln1_g + (l + 1) * 256, ln1_b + (l + 1) * 256, 1024,
          nullptr, nullptr, nullptr, nullptr);
    else
      // h += ffb @ ff2_w^T + ff2_b ; hb mirror ; logits = h @ pool_w + pb
      gemm_rln<true><<<N_NODES / 32, 256, 0, stream>>>(
          ffb, ff2_w + (size_t)l * 256 * 1024, ff2_b + l * 256, h, nullptr,
          nullptr, nullptr, 1024,
          hb, pool_w, pool_b, logits);
  }

  pool_reduce<<<1, 1024, 0, stream>>>(logits, redb);
  pool_grep<<<256, 256, 0, stream>>>(h, logits, redb, g_rep);
  heads_fused<<<8, 256, 0, stream>>>(
      g_rep, vw1, vb1, vw2, vb2, uw1, ub1, uw2, ub2, o_val, o_unc);
  gemm_pol<<<N_NODES / 32, 256, 0, stream>>>(hb, pw1, pb1, pw2, pb2, o_pol);

  emit_out<<<(OUT_ELEMS + 255) / 256, 256, 0, stream>>>(
      (const unsigned short*)ostage, d_out, OUT_ELEMS, flags);
}